// Round 18
// baseline (262.161 us; speedup 1.0000x reference)
//
#include <hip/hip_runtime.h>

typedef __attribute__((ext_vector_type(8))) short short8;
typedef __attribute__((ext_vector_type(4))) short short4v;
typedef __attribute__((ext_vector_type(4))) float float4v;
typedef __attribute__((ext_vector_type(2))) unsigned int uint2v;
typedef __attribute__((ext_vector_type(8))) __bf16 bf16x8;

#define LDS_PQ 57344
#define LDS_PK 107520
#define LDS_TOTAL 157696

__device__ __forceinline__ unsigned short f2bf(float f) {
  unsigned u = __float_as_uint(f);
  u += 0x7FFFu + ((u >> 16) & 1u);   // RNE
  return (unsigned short)(u >> 16);
}

__device__ __forceinline__ unsigned cvtpk(float lo, float hi) {
  unsigned r;
  asm("v_cvt_pk_bf16_f32 %0, %1, %2" : "=v"(r) : "v"(lo), "v"(hi));
  return r;
}

__device__ __forceinline__ int pswz(int s) { return ((s ^ (s >> 3)) & 7) << 4; }

// ---- kernel 1: convert + pre-swizzle weights to bf16 fragment order; W_q pre-scaled 0.125 ----
__global__ void wconv_kernel(const float* __restrict__ qw, const float* __restrict__ kw,
                             const float* __restrict__ vw, short* __restrict__ out) {
  int idx = blockIdx.x * 256 + threadIdx.x;
  int g = idx >> 15;
  int rem = idx & 32767;
  int lane = rem & 63;
  int n01 = (rem >> 6) & 1;
  int w   = (rem >> 7) & 15;
  int kk  = rem >> 11;
  int o  = w * 32 + n01 * 16 + (lane & 15);
  int k0 = kk * 32 + (lane >> 4) * 8;
  const float* src = (g == 0) ? qw : (g == 1) ? kw : vw;
  const float sc = (g == 0) ? 0.125f : 1.0f;
  const float* p = src + o * 512 + k0;
  float4v v0 = *(const float4v*)(p);
  float4v v1 = *(const float4v*)(p + 4);
  short8 o8;
  o8[0] = (short)f2bf(v0.x * sc); o8[1] = (short)f2bf(v0.y * sc);
  o8[2] = (short)f2bf(v0.z * sc); o8[3] = (short)f2bf(v0.w * sc);
  o8[4] = (short)f2bf(v1.x * sc); o8[5] = (short)f2bf(v1.y * sc);
  o8[6] = (short)f2bf(v1.z * sc); o8[7] = (short)f2bf(v1.w * sc);
  *(short8*)(out + idx * 8) = o8;
}

// ---- kernel 1b: expand relative-position bias to bexp[h][i][j], j padded to 56 ----
__global__ void bexp_kernel(const float* __restrict__ btab, float* __restrict__ bexp) {
  int idx = blockIdx.x * 256 + threadIdx.x;   // 86*256 = 22016 exactly
  float v = 0.f;
  if (idx < 21952) {
    int h = idx / 2744;
    int rem = idx - h * 2744;
    int i = rem / 56;
    int j = rem - i * 56;
    if (j < 49) {
      int yi = (i * 37) >> 8, xi = i - yi * 7;
      int yj = (j * 37) >> 8, xj = j - yj * 7;
      int t = (yi - yj + 6) * 13 + (xi - xj + 6);
      v = btab[t * 8 + h];
    }
  }
  bexp[idx] = v;
}

// ================== SPLIT PATH kernel A: per-window QKV projection ==================
// CRITICAL MAPPING (r17 bug): the head split is a FLAT reinterpretation -- head h,
// token t' lives at CHUNK s = h*49+t' of the row-major [49*8][64] flattening, i.e.
// t = s>>3, o-block sg = s&7. Heads are NOT o-col blocks. So Q/K are stored
// CHUNK-INDEXED [bwi][s=392][64] (s = t*8 + wave), and V scatters per element to
// [bh=bwi*8+h2][dd][tp] with h2 = s/49, tp = s%49 (same math as the fused VT).
// 8 waves/512 thr, LDS = XT only (50176 B). wave = o-block sg; 6 passes (g x mh).
__global__ __launch_bounds__(512, 4) void qkv_kernel(
    const float* __restrict__ x, const short* __restrict__ wcvt,
    const float* __restrict__ qb, const float* __restrict__ kb, const float* __restrict__ vb,
    short* __restrict__ qg, short* __restrict__ kg, short* __restrict__ vg) {
  __shared__ __align__(16) char sm[50176];
  const int tid  = threadIdx.x;
  const int lane = tid & 63;
  const int wave = tid >> 6;       // 0..7 = o-block sg (o-cols wave*64 .. +64)
  const int bwi  = blockIdx.x;
  const int bb   = bwi >> 6, wi = bwi & 63;
  const int l15  = lane & 15;
  const int l4   = lane >> 4;
  const int ig   = l4 * 4;
  const int ckof = l4 * 16;

  // stage x tile -> XT bf16 [49][512], row-XOR swizzle
  {
    const float* xb = x + (size_t)bb * (3136 * 512);
    const int whi = (wi >> 3) * 7, wlo = (wi & 7) * 7;
    for (int idx = tid; idx < 6272; idx += 512) {
      int t = idx >> 7, c4 = idx & 127;
      int yt = (t * 37) >> 8, xt = t - yt * 7;
      int l = (whi + yt) * 56 + wlo + xt;
      float4v v = *(const float4v*)(xb + l * 512 + c4 * 4);
      uint2v o;
      o.x = cvtpk(v.x, v.y);
      o.y = cvtpk(v.z, v.w);
      int byte = t * 1024 + c4 * 8;
      *(uint2v*)(sm + (byte ^ ((t & 7) << 4))) = o;
    }
  }
  __syncthreads();

  const short* wh = wcvt + wave * 2048 + lane * 8;   // o-block 'wave': 4 contiguous frags

#pragma unroll 1
  for (int p = 0; p < 6; ++p) {
    const int g = p >> 1, mh = p & 1;
    const short* wgb = wh + g * 262144;
    const float* bias = (g == 0) ? qb : (g == 1) ? kb : vb;
    int xb0[2], xs0[2];
#pragma unroll
    for (int mt = 0; mt < 2; ++mt) {
      int row = mh * 32 + mt * 16 + l15;   // rows >=49 read junk; discarded at store
      xb0[mt] = row * 1024;
      xs0[mt] = (row & 7) << 4;
    }
    float4v acc[4][2];
#pragma unroll
    for (int nt = 0; nt < 4; ++nt)
#pragma unroll
      for (int mt = 0; mt < 2; ++mt) acc[nt][mt] = (float4v)0.f;

#pragma unroll 1
    for (int kk = 0; kk < 16; ++kk) {
      const short* wp = wgb + kk * 16384;
      bf16x8 w0 = __builtin_bit_cast(bf16x8, *(const short8*)(wp));
      bf16x8 w1 = __builtin_bit_cast(bf16x8, *(const short8*)(wp + 512));
      bf16x8 w2 = __builtin_bit_cast(bf16x8, *(const short8*)(wp + 1024));
      bf16x8 w3 = __builtin_bit_cast(bf16x8, *(const short8*)(wp + 1536));
      const int c_ = kk * 64 + ckof;
      bf16x8 x0 = __builtin_bit_cast(bf16x8, *(const short8*)(sm + xb0[0] + (c_ ^ xs0[0])));
      bf16x8 x1 = __builtin_bit_cast(bf16x8, *(const short8*)(sm + xb0[1] + (c_ ^ xs0[1])));
      __builtin_amdgcn_s_setprio(1);
      acc[0][0] = __builtin_amdgcn_mfma_f32_16x16x32_bf16(w0, x0, acc[0][0], 0, 0, 0);
      acc[1][0] = __builtin_amdgcn_mfma_f32_16x16x32_bf16(w1, x0, acc[1][0], 0, 0, 0);
      acc[2][0] = __builtin_amdgcn_mfma_f32_16x16x32_bf16(w2, x0, acc[2][0], 0, 0, 0);
      acc[3][0] = __builtin_amdgcn_mfma_f32_16x16x32_bf16(w3, x0, acc[3][0], 0, 0, 0);
      acc[0][1] = __builtin_amdgcn_mfma_f32_16x16x32_bf16(w0, x1, acc[0][1], 0, 0, 0);
      acc[1][1] = __builtin_amdgcn_mfma_f32_16x16x32_bf16(w1, x1, acc[1][1], 0, 0, 0);
      acc[2][1] = __builtin_amdgcn_mfma_f32_16x16x32_bf16(w2, x1, acc[2][1], 0, 0, 0);
      acc[3][1] = __builtin_amdgcn_mfma_f32_16x16x32_bf16(w3, x1, acc[3][1], 0, 0, 0);
      __builtin_amdgcn_s_setprio(0);
    }

#pragma unroll
    for (int nt = 0; nt < 4; ++nt) {
      int dd0 = nt * 16 + ig;
      float4v bv = *(const float4v*)(bias + wave * 64 + dd0);
      if (g == 0) {
#pragma unroll
        for (int r = 0; r < 4; ++r) bv[r] *= 0.125f;   // match pre-scaled W_q
      }
      if (g < 2) {
        // chunk-indexed store: row s = t*8 + wave of [bwi][392][64]
        short* dstbase = ((g == 0) ? qg : kg) +
                         ((size_t)bwi * 392 + wave) * 64 + dd0;
#pragma unroll
        for (int mt = 0; mt < 2; ++mt) {
          int t = mh * 32 + mt * 16 + l15;
          if (t < 49) {
            uint2v p2;
            p2.x = cvtpk(acc[nt][mt][0] + bv[0], acc[nt][mt][1] + bv[1]);
            p2.y = cvtpk(acc[nt][mt][2] + bv[2], acc[nt][mt][3] + bv[3]);
            *(uint2v*)(dstbase + (size_t)t * 512) = p2;   // t*8 chunks * 64
          }
        }
      } else {
        // V scatter: chunk s -> (h2 = s/49, tp = s%49); layout [bh][dd][tp]
#pragma unroll
        for (int mt = 0; mt < 2; ++mt) {
          int t = mh * 32 + mt * 16 + l15;
          if (t < 49) {
            int s = t * 8 + wave;
            int h2 = (s * 1339) >> 16;       // s / 49
            int tp = s - h2 * 49;
            short* vp = vg + (size_t)(bwi * 8 + h2) * 3584 + tp;
#pragma unroll
            for (int r = 0; r < 4; ++r)
              vp[(size_t)(dd0 + r) * 56] = (short)f2bf(acc[nt][mt][r] + bv[r]);
          }
        }
      }
    }
  }

  // zero V pads tp 49..55 (o-block wave's dd rows map across heads; zero per (h2,dd)):
  // each thread handles one (h2 = wave, dd = lane) pair -- but pads are per (bh, dd),
  // so use (bwi*8 + wave) with wave as h2 here (covers all 8 heads x 64 dd).
  {
    short* vp = vg + (size_t)(bwi * 8 + wave) * 3584 + (size_t)lane * 56;
#pragma unroll
    for (int q = 49; q < 56; ++q) vp[q] = 0;
  }
  // tail pad past the last V row (vf ks=1/l4=3 over-reads 16 B)
  if (bwi == 1023 && tid < 64) vg[(size_t)8192 * 3584 + tid] = 0;
}

// ================== SPLIT PATH kernel B: per-(window,head) attention ==================
// 4 independent waves/block, each owns one (bwi,h): private 8-KB overlay, no
// cross-wave coupling. Head h = chunk rows s = h*49 .. h*49+48 of [bwi][392][64].
// Junk rows (i,j >= 49) read neighboring chunks / tail pad -- masked BY INDEX in
// softmax, so any bit pattern there is safe. V is the only finite-required input.
__global__ __launch_bounds__(256, 4) void attn2_kernel(
    const short* __restrict__ qg, const short* __restrict__ kg, const short* __restrict__ vg,
    const float* __restrict__ bexp, float* __restrict__ out) {
  __shared__ __align__(16) char ovs[4][8192];
  const int tid  = threadIdx.x;
  const int lane = tid & 63;
  const int wave = tid >> 6;
  const int bh   = blockIdx.x * 4 + wave;   // [0, 8192)
  const int h    = bh & 7, bwi = bh >> 3;
  const int l15  = lane & 15;
  const int l4   = lane >> 4;
  const int ig   = l4 * 4;
  char* ov = ovs[wave];

  const short* Qh = qg + ((size_t)bwi * 392 + h * 49) * 64;
  const short* Kh = kg + ((size_t)bwi * 392 + h * 49) * 64;
  const short* Vh = vg + (size_t)bh * 3584;

  // QK^T swapped: D[row=j][col=i]; scr[jt][it]; i = it*16+l15, j = jt*16+ig+r
  float4v scr[4][4];
#pragma unroll
  for (int jt = 0; jt < 4; ++jt)
#pragma unroll
    for (int it = 0; it < 4; ++it) scr[jt][it] = (float4v)0.f;

#pragma unroll
  for (int ks = 0; ks < 2; ++ks) {
    const int dd = ks * 32 + l4 * 8;
    bf16x8 kf[4], qf[4];
#pragma unroll
    for (int jt = 0; jt < 4; ++jt)   // rows >=49: neighboring chunks, masked by index
      kf[jt] = __builtin_bit_cast(bf16x8, *(const short8*)(Kh + (size_t)(jt * 16 + l15) * 64 + dd));
#pragma unroll
    for (int it = 0; it < 4; ++it)
      qf[it] = __builtin_bit_cast(bf16x8, *(const short8*)(Qh + (size_t)(it * 16 + l15) * 64 + dd));
    __builtin_amdgcn_s_setprio(1);
#pragma unroll
    for (int jt = 0; jt < 4; ++jt)
#pragma unroll
      for (int it = 0; it < 4; ++it)
        scr[jt][it] = __builtin_amdgcn_mfma_f32_16x16x32_bf16(kf[jt], qf[it], scr[jt][it], 0, 0, 0);
    __builtin_amdgcn_s_setprio(0);
  }

  // softmax per column i (scores pre-scaled via W_q); bias from bexp[h][i][j]
  const float* bx = bexp + h * 2744;
#pragma unroll
  for (int it = 0; it < 4; ++it) {
    int i = it * 16 + l15;
    const float* bi = bx + ((i > 48) ? 48 : i) * 56 + ig;
    float mx = -1e30f;
#pragma unroll
    for (int jt = 0; jt < 4; ++jt) {
      float4v b4 = *(const float4v*)(bi + jt * 16);
#pragma unroll
      for (int r = 0; r < 4; ++r) {
        int j = jt * 16 + ig + r;
        float v = (i < 49 && j < 49) ? scr[jt][it][r] + b4[r] : -1e30f;
        scr[jt][it][r] = v;
        mx = fmaxf(mx, v);
      }
    }
    mx = fmaxf(mx, __shfl_xor(mx, 16));
    mx = fmaxf(mx, __shfl_xor(mx, 32));
    float ssum = 0.f;
#pragma unroll
    for (int jt = 0; jt < 4; ++jt)
#pragma unroll
      for (int r = 0; r < 4; ++r) {
        float e = __expf(scr[jt][it][r] - mx);
        scr[jt][it][r] = e;
        ssum += e;
      }
    ssum += __shfl_xor(ssum, 16);
    ssum += __shfl_xor(ssum, 32);
    float inv = 1.f / ssum;
#pragma unroll
    for (int jt = 0; jt < 4; ++jt)
#pragma unroll
      for (int r = 0; r < 4; ++r) scr[jt][it][r] *= inv;
  }

  // overlay attn [64][64] bf16 (row-XOR swz) in this wave's private 8 KB
#pragma unroll
  for (int it = 0; it < 4; ++it) {
    int i = it * 16 + l15;
    if (i < 49) {
      int rowb = i * 128, swz = (i & 7) << 4;
#pragma unroll
      for (int jt = 0; jt < 4; ++jt) {
        uint2v p2;
        p2.x = cvtpk(scr[jt][it][0], scr[jt][it][1]);
        p2.y = cvtpk(scr[jt][it][2], scr[jt][it][3]);
        *(uint2v*)(ov + ((rowb + jt * 32 + ig * 2) ^ swz)) = p2;
      }
    }
  }
  __syncthreads();

  // PV swapped: A = VT[dd][tp] (dt-tiles), B = attn rows (tt-tiles); D = out^T
  float4v oacc[4][4];
#pragma unroll
  for (int dt = 0; dt < 4; ++dt)
#pragma unroll
    for (int tt = 0; tt < 4; ++tt) oacc[dt][tt] = (float4v)0.f;

#pragma unroll
  for (int ks = 0; ks < 2; ++ks) {
    const int tp0 = ks * 32 + l4 * 8;   // tp 49..55 zeroed; tp0=56 over-reads finite pad
    bf16x8 vf[4], af[4];
#pragma unroll
    for (int dt = 0; dt < 4; ++dt)
      vf[dt] = __builtin_bit_cast(bf16x8, *(const short8*)(Vh + (size_t)(dt * 16 + l15) * 56 + tp0));
#pragma unroll
    for (int tt = 0; tt < 4; ++tt) {
      int t = tt * 16 + l15;
      int tr = (t > 48) ? 48 : t;       // junk cols read row 48; discarded
      af[tt] = __builtin_bit_cast(bf16x8,
          *(const short8*)(ov + ((tr * 128 + tp0 * 2) ^ ((tr & 7) << 4))));
    }
    __builtin_amdgcn_s_setprio(1);
#pragma unroll
    for (int dt = 0; dt < 4; ++dt)
#pragma unroll
      for (int tt = 0; tt < 4; ++tt)
        oacc[dt][tt] = __builtin_amdgcn_mfma_f32_16x16x32_bf16(vf[dt], af[tt], oacc[dt][tt], 0, 0, 0);
    __builtin_amdgcn_s_setprio(0);
  }

  float* op = out + (size_t)bwi * 25088 + h * 3136;
#pragma unroll
  for (int tt = 0; tt < 4; ++tt) {
    int t = tt * 16 + l15;
    if (t < 49) {
#pragma unroll
      for (int dt = 0; dt < 4; ++dt)
        *(float4v*)(op + t * 64 + dt * 16 + ig) = oacc[dt][tt];
    }
  }
}

// ================== FALLBACK: r16 fused kernel (147 us floor) ==================
__global__ __launch_bounds__(1024, 4) void wattn_kernel(
    const float* __restrict__ x, const short* __restrict__ wcvt,
    const float* __restrict__ qb, const float* __restrict__ kb, const float* __restrict__ vb,
    const float* __restrict__ bexp, float* __restrict__ out) {
  __shared__ __align__(16) char sm[LDS_TOTAL];
  const int tid  = threadIdx.x;
  const int lane = tid & 63;
  const int wave = tid >> 6;
  const int bwi  = blockIdx.x;
  const int bb   = bwi >> 6, wi = bwi & 63;
  const int l15  = lane & 15;
  const int l4   = lane >> 4;
  const int ig   = l4 * 4;
  const int wcol = wave * 32;
  const int ckof = l4 * 16;
  const int h    = wave & 7;
  const int mh   = wave >> 3;

  {
    const float* xb = x + (size_t)bb * (3136 * 512);
    const int whi = (wi >> 3) * 7, wlo = (wi & 7) * 7;
    for (int idx = tid; idx < 49 * 128; idx += 1024) {
      int t = idx >> 7, c4 = idx & 127;
      int yt = (t * 37) >> 8, xt = t - yt * 7;
      int l = (whi + yt) * 56 + wlo + xt;
      float4v v = *(const float4v*)(xb + l * 512 + c4 * 4);
      uint2v o;
      o.x = cvtpk(v.x, v.y);
      o.y = cvtpk(v.z, v.w);
      int byte = t * 1024 + c4 * 8;
      *(uint2v*)(sm + (byte ^ ((t & 7) << 4))) = o;
    }
  }
  __syncthreads();

  int xbase[4], xsw[4];
#pragma unroll
  for (int mt = 0; mt < 4; ++mt) {
    int row = mt * 16 + l15;
    xbase[mt] = row * 1024;
    xsw[mt]   = (row & 7) << 4;
  }

  const short* wgb0 = wcvt + wave * 1024 + lane * 8;

#define LDWP(P, OFF) __builtin_bit_cast(bf16x8, *(const short8*)((P) + (OFF)))
#define LDX(MT, C) __builtin_bit_cast(bf16x8, *(const short8*)(sm + xbase[MT] + ((C) ^ xsw[MT])))

  {
    const short* wq = wgb0;
    const short* wk = wgb0 + 262144;
    float4v aq[2][4], ak[2][4];
#pragma unroll
    for (int nt = 0; nt < 2; ++nt)
#pragma unroll
      for (int mt = 0; mt < 4; ++mt) { aq[nt][mt] = (float4v)0.f; ak[nt][mt] = (float4v)0.f; }

    bf16x8 uq0 = LDWP(wq, 0), uq1 = LDWP(wq, 512);
    bf16x8 uk0 = LDWP(wk, 0), uk1 = LDWP(wk, 512);

#pragma unroll 1
    for (int kk = 0; kk < 16; ++kk) {
      const int nko = ((kk + 1) & 15) * 16384;
      bf16x8 nq0 = LDWP(wq, nko), nq1 = LDWP(wq, nko + 512);
      bf16x8 nk0 = LDWP(wk, nko), nk1 = LDWP(wk, nko + 512);
      const int c_ = kk * 64 + ckof;
      bf16x8 x0 = LDX(0, c_), x1 = LDX(1, c_), x2 = LDX(2, c_), x3 = LDX(3, c_);
      __builtin_amdgcn_s_setprio(1);
      aq[0][0] = __builtin_amdgcn_mfma_f32_16x16x32_bf16(uq0, x0, aq[0][0], 0, 0, 0);
      aq[1][0] = __builtin_amdgcn_mfma_f32_16x16x32_bf16(uq1, x0, aq[1][0], 0, 0, 0);
      ak[0][0] = __builtin_amdgcn_mfma_f32_16x16x32_bf16(uk0, x0, ak[0][0], 0, 0, 0);
      ak[1][0] = __builtin_amdgcn_mfma_f32_16x16x32_bf16(uk1, x0, ak[1][0], 0, 0, 0);
      aq[0][1] = __builtin_amdgcn_mfma_f32_16x16x32_bf16(uq0, x1, aq[0][1], 0, 0, 0);
      aq[1][1] = __builtin_amdgcn_mfma_f32_16x16x32_bf16(uq1, x1, aq[1][1], 0, 0, 0);
      ak[0][1] = __builtin_amdgcn_mfma_f32_16x16x32_bf16(uk0, x1, ak[0][1], 0, 0, 0);
      ak[1][1] = __builtin_amdgcn_mfma_f32_16x16x32_bf16(uk1, x1, ak[1][1], 0, 0, 0);
      aq[0][2] = __builtin_amdgcn_mfma_f32_16x16x32_bf16(uq0, x2, aq[0][2], 0, 0, 0);
      aq[1][2] = __builtin_amdgcn_mfma_f32_16x16x32_bf16(uq1, x2, aq[1][2], 0, 0, 0);
      ak[0][2] = __builtin_amdgcn_mfma_f32_16x16x32_bf16(uk0, x2, ak[0][2], 0, 0, 0);
      ak[1][2] = __builtin_amdgcn_mfma_f32_16x16x32_bf16(uk1, x2, ak[1][2], 0, 0, 0);
      aq[0][3] = __builtin_amdgcn_mfma_f32_16x16x32_bf16(uq0, x3, aq[0][3], 0, 0, 0);
      aq[1][3] = __builtin_amdgcn_mfma_f32_16x16x32_bf16(uq1, x3, aq[1][3], 0, 0, 0);
      ak[0][3] = __builtin_amdgcn_mfma_f32_16x16x32_bf16(uk0, x3, ak[0][3], 0, 0, 0);
      ak[1][3] = __builtin_amdgcn_mfma_f32_16x16x32_bf16(uk1, x3, ak[1][3], 0, 0, 0);
      __builtin_amdgcn_s_setprio(0);
      uq0 = nq0; uq1 = nq1; uk0 = nk0; uk1 = nk1;
    }

#pragma unroll
    for (int nt = 0; nt < 2; ++nt) {
      int o0 = wcol + nt * 16 + ig;
      float4v bq = *(const float4v*)(qb + o0);
      float4v bk = *(const float4v*)(kb + o0);
#pragma unroll
      for (int r = 0; r < 4; ++r) bq[r] *= 0.125f;
      int dd0 = o0 & 63, sg = o0 >> 6;
#pragma unroll
      for (int mt = 0; mt < 4; ++mt) {
        int t = mt * 16 + l15;
        if (t < 49) {
          int s = t * 8 + sg;
          int addr = (s * 128 + dd0 * 2) ^ pswz(s);
          uint2v pq, pk;
          pq.x = cvtpk(aq[nt][mt][0] + bq[0], aq[nt][mt][1] + bq[1]);
          pq.y = cvtpk(aq[nt][mt][2] + bq[2], aq[nt][mt][3] + bq[3]);
          pk.x = cvtpk(ak[nt][mt][0] + bk[0], ak[nt][mt][1] + bk[1]);
          pk.y = cvtpk(ak[nt][mt][2] + bk[2], ak[nt][mt][3] + bk[3]);
          *(uint2v*)(sm + LDS_PQ + addr) = pq;
          *(uint2v*)(sm + LDS_PK + addr) = pk;
        }
      }
    }
  }

  float4v acc[2][4];
  {
    const short* wgb = wgb0 + 2 * 262144;
#pragma unroll
    for (int nt = 0; nt < 2; ++nt)
#pragma unroll
      for (int mt = 0; mt < 4; ++mt) acc[nt][mt] = (float4v)0.f;

    bf16x8 wa0 = LDWP(wgb, 0),     wa1 = LDWP(wgb, 512);
    bf16x8 wb0 = LDWP(wgb, 16384), wb1 = LDWP(wgb, 16384 + 512);
    bf16x8 wc0, wc1, wd0, wd1;

#define GEMM_PHASE(KIDX, W0, W1)                                                          \
    do {                                                                                  \
      const int c_ = (KIDX) * 64 + ckof;                                                  \
      bf16x8 x0_ = LDX(0, c_), x1_ = LDX(1, c_), x2_ = LDX(2, c_), x3_ = LDX(3, c_);      \
      __builtin_amdgcn_s_setprio(1);                                                      \
      acc[0][0] = __builtin_amdgcn_mfma_f32_16x16x32_bf16(W0, x0_, acc[0][0], 0, 0, 0);   \
      acc[1][0] = __builtin_amdgcn_mfma_f32_16x16x32_bf16(W1, x0_, acc[1][0], 0, 0, 0);   \
      acc[0][1] = __builtin_amdgcn_mfma_f32_16x16x32_bf16(W0, x1_, acc[0][1], 0, 0, 0);   \
      acc[1][1] = __builtin_amdgcn_mfma_f32_16x16x32_bf16(W1, x1_, acc[1][1], 0, 0, 0);   \
      acc[0][2] = __builtin_amdgcn_mfma_f32_16x16x32_bf16(W0, x2_, acc[0][2], 0, 0, 0);   \
      acc[1][2] = __builtin_amdgcn_mfma_f32_16x16x32_bf16(W1, x2_, acc[1][2], 0, 0, 0);   \
      acc[0][3] = __builtin_amdgcn_mfma_f32_16x16x32_bf16(W0, x3_, acc[0][3], 0, 0, 0);   \
      acc[1][3] = __builtin_amdgcn_mfma_f32_16x16x32_bf16(W1, x3_, acc[1][3], 0, 0, 0);   \
      __builtin_amdgcn_s_setprio(0);                                                      \
    } while (0)

#pragma unroll 1
    for (int kk = 0; kk < 16; kk += 4) {
      wc0 = LDWP(wgb, ((kk + 2) & 15) * 16384); wc1 = LDWP(wgb, ((kk + 2) & 15) * 16384 + 512);
      GEMM_PHASE(kk, wa0, wa1);
      wd0 = LDWP(wgb, ((kk + 3) & 15) * 16384); wd1 = LDWP(wgb, ((kk + 3) & 15) * 16384 + 512);
      GEMM_PHASE(kk + 1, wb0, wb1);
      wa0 = LDWP(wgb, ((kk + 4) & 15) * 16384); wa1 = LDWP(wgb, ((kk + 4) & 15) * 16384 + 512);
      GEMM_PHASE(kk + 2, wc0, wc1);
      wb0 = LDWP(wgb, ((kk + 5) & 15) * 16384); wb1 = LDWP(wgb, ((kk + 5) & 15) * 16384 + 512);
      GEMM_PHASE(kk + 3, wd0, wd1);
    }
#undef GEMM_PHASE
  }

  __syncthreads();

  float4v scr[4][2];
#pragma unroll
  for (int jt = 0; jt < 4; ++jt)
#pragma unroll
    for (int it = 0; it < 2; ++it) scr[jt][it] = (float4v)0.f;

#pragma unroll
  for (int ks = 0; ks < 2; ++ks) {
    const int dd = ks * 32 + l4 * 8;
    bf16x8 kf[4], qf[2];
#pragma unroll
    for (int jt = 0; jt < 4; ++jt) {
      int s = h * 49 + jt * 16 + l15;
      int flat = s * 128 + dd * 2;
      kf[jt] = __builtin_bit_cast(bf16x8, *(const short8*)(sm + LDS_PK + (flat ^ pswz(s))));
    }
#pragma unroll
    for (int it = 0; it < 2; ++it) {
      int s = h * 49 + (mh * 2 + it) * 16 + l15;
      int flat = s * 128 + dd * 2;
      qf[it] = __builtin_bit_cast(bf16x8, *(const short8*)(sm + LDS_PQ + (flat ^ pswz(s))));
    }
    __builtin_amdgcn_s_setprio(1);
#pragma unroll
    for (int jt = 0; jt < 4; ++jt)
#pragma unroll
      for (int it = 0; it < 2; ++it)
        scr[jt][it] = __builtin_amdgcn_mfma_f32_16x16x32_bf16(kf[jt], qf[it], scr[jt][it], 0, 0, 0);
    __builtin_amdgcn_s_setprio(0);
  }

  {
#pragma unroll
    for (int nt = 0; nt < 2; ++nt) {
      int o0 = wcol + nt * 16 + ig;
      float4v bv = *(const float4v*)(vb + o0);
      int dd0 = o0 & 63, sg = o0 >> 6;
#pragma unroll
      for (int mt = 0; mt < 4; ++mt) {
        int t = mt * 16 + l15;
        if (t < 49) {
          int s = t * 8 + sg;
          int h2 = (s * 1339) >> 16;
          int colb = h2 * 112 + (s - h2 * 49) * 2;
#pragma unroll
          for (int r = 0; r < 4; ++r) {
            int dd = dd0 + r;
            *(unsigned short*)(sm + ((dd * 896 + colb) ^ ((dd & 7) << 4))) =
                f2bf(acc[nt][mt][r] + bv[r]);
          }
        }
      }
    }
    for (int idx = tid; idx < 3584; idx += 1024) {
      int q = idx >> 9;
      int rem = idx & 511;
      int h2 = rem >> 6, dd = rem & 63;
      *(unsigned short*)(sm + ((dd * 896 + h2 * 112 + (49 + q) * 2) ^ ((dd & 7) << 4))) = 0;
    }
  }

  const float* bx = bexp + h * 2744;
#pragma unroll
  for (int it = 0; it < 2; ++it) {
    int i = (mh * 2 + it) * 16 + l15;
    const float* bi = bx + ((i > 48) ? 48 : i) * 56 + ig;
    float mx = -1e30f;
#pragma unroll
    for (int jt = 0; jt < 4; ++jt) {
      float4v b4 = *(const float4v*)(bi + jt * 16);
#pragma unroll
      for (int r = 0; r < 4; ++r) {
        int j = jt * 16 + ig + r;
        float v = (i < 49 && j < 49) ? scr[jt][it][r] + b4[r] : -1e30f;
        scr[jt][it][r] = v;
        mx = fmaxf(mx, v);
      }
    }
    mx = fmaxf(mx, __shfl_xor(mx, 16));
    mx = fmaxf(mx, __shfl_xor(mx, 32));
    float ssum = 0.f;
#pragma unroll
    for (int jt = 0; jt < 4; ++jt)
#pragma unroll
      for (int r = 0; r < 4; ++r) {
        float e = __expf(scr[jt][it][r] - mx);
        scr[jt][it][r] = e;
        ssum += e;
      }
    ssum += __shfl_xor(ssum, 16);
    ssum += __shfl_xor(ssum, 32);
    float inv = 1.f / ssum;
#pragma unroll
    for (int jt = 0; jt < 4; ++jt)
#pragma unroll
      for (int r = 0; r < 4; ++r) scr[jt][it][r] *= inv;
  }

#pragma unroll
  for (int it = 0; it < 2; ++it) {
    int i = (mh * 2 + it) * 16 + l15;
    if (i < 49) {
      int s = h * 49 + i;
      int rowb = s * 128;
      int swz = pswz(s);
#pragma unroll
      for (int jt = 0; jt < 4; ++jt) {
        uint2v pk2;
        pk2.x = cvtpk(scr[jt][it][0], scr[jt][it][1]);
        pk2.y = cvtpk(scr[jt][it][2], scr[jt][it][3]);
        *(uint2v*)(sm + LDS_PQ + ((rowb + jt * 32 + ig * 2) ^ swz)) = pk2;
      }
    }
  }

  __syncthreads();

  float4v oacc[4][2];
#pragma unroll
  for (int dt = 0; dt < 4; ++dt)
#pragma unroll
    for (int tt = 0; tt < 2; ++tt) oacc[dt][tt] = (float4v)0.f;

#pragma unroll
  for (int ks = 0; ks < 2; ++ks) {
    const int tp0 = ks * 32 + l4 * 8;
    bf16x8 vf[4], af[2];
#pragma unroll
    for (int dt = 0; dt < 4; ++dt) {
      int dd = dt * 16 + l15;
      vf[dt] = __builtin_bit_cast(bf16x8,
          *(const short8*)(sm + ((dd * 896 + h * 112 + tp0 * 2) ^ ((dd & 7) << 4))));
    }
#pragma unroll
    for (int tt = 0; tt < 2; ++tt) {
      int t = (mh * 2 + tt) * 16 + l15;
      int tr = (t > 48) ? 48 : t;
      int s = h * 49 + tr;
      af[tt] = __builtin_bit_cast(bf16x8,
          *(const short8*)(sm + LDS_PQ + ((s * 128 + tp0 * 2) ^ pswz(s))));
    }
    __builtin_amdgcn_s_setprio(1);
#pragma unroll
    for (int dt = 0; dt < 4; ++dt)
#pragma unroll
      for (int tt = 0; tt < 2; ++tt)
        oacc[dt][tt] = __builtin_amdgcn_mfma_f32_16x16x32_bf16(vf[dt], af[tt], oacc[dt][tt], 0, 0, 0);
    __builtin_amdgcn_s_setprio(0);
  }

  float* op = out + (size_t)bwi * 25088 + h * 3136;
#pragma unroll
  for (int tt = 0; tt < 2; ++tt) {
    int t = (mh * 2 + tt) * 16 + l15;
    if (t < 49) {
#pragma unroll
      for (int dt = 0; dt < 4; ++dt)
        *(float4v*)(op + t * 64 + dt * 16 + ig) = oacc[dt][tt];
    }
  }
#undef LDWP
#undef LDX
}

extern "C" void kernel_launch(void* const* d_in, const int* in_sizes, int n_in,
                              void* d_out, int out_size, void* d_ws, size_t ws_size,
                              hipStream_t stream) {
  const float* x    = (const float*)d_in[0];
  const float* q_w  = (const float*)d_in[1];
  const float* q_b  = (const float*)d_in[2];
  const float* k_w  = (const float*)d_in[3];
  const float* k_b  = (const float*)d_in[4];
  const float* v_w  = (const float*)d_in[5];
  const float* v_b  = (const float*)d_in[6];
  const float* btab = (const float*)d_in[7];
  short* wcvt = (short*)d_ws;                              // 1.5 MB fragment-order weights
  float* bexp = (float*)((char*)d_ws + 3 * 262144 * 2);    // 22016 f32 bias table

  hipLaunchKernelGGL(wconv_kernel, dim3(384), dim3(256), 0, stream, q_w, k_w, v_w, wcvt);
  hipLaunchKernelGGL(bexp_kernel, dim3(86), dim3(256), 0, stream, btab, bexp);

  // split path: Qg/Kg = 1024*392*64 bf16 (51.38 MB each, +4K overrun pad),
  // Vg = 8192*64*56 bf16 (58.72 MB, +4K pad)
  const size_t QG_OFF = 2097152;
  const size_t KG_OFF = QG_OFF + 51380224 + 4096;          // 53,481,472
  const size_t VG_OFF = KG_OFF + 51380224 + 4096;          // 104,865,792
  const size_t REQUIRED = VG_OFF + 58720256 + 4096;        // 163,590,144
  if (ws_size >= REQUIRED) {
    short* qg = (short*)((char*)d_ws + QG_OFF);
    short* kg = (short*)((char*)d_ws + KG_OFF);
    short* vg = (short*)((char*)d_ws + VG_OFF);
    hipLaunchKernelGGL(qkv_kernel, dim3(1024), dim3(512), 0, stream,
                       x, wcvt, q_b, k_b, v_b, qg, kg, vg);
    hipLaunchKernelGGL(attn2_kernel, dim3(2048), dim3(256), 0, stream,
                       qg, kg, vg, bexp, (float*)d_out);
  } else {
    hipLaunchKernelGGL(wattn_kernel, dim3(1024), dim3(1024), 0, stream,
                       x, wcvt, q_b, k_b, v_b, bexp, (float*)d_out);
  }
}

// Round 19
// 199.885 us; speedup vs baseline: 1.3116x; 1.3116x over previous
//
#include <hip/hip_runtime.h>

typedef __attribute__((ext_vector_type(8))) short short8;
typedef __attribute__((ext_vector_type(4))) short short4v;
typedef __attribute__((ext_vector_type(4))) float float4v;
typedef __attribute__((ext_vector_type(2))) unsigned int uint2v;
typedef __attribute__((ext_vector_type(8))) __bf16 bf16x8;

#define LDS_PQ 57344
#define LDS_PK 107520
#define LDS_TOTAL 157696

__device__ __forceinline__ unsigned short f2bf(float f) {
  unsigned u = __float_as_uint(f);
  u += 0x7FFFu + ((u >> 16) & 1u);   // RNE
  return (unsigned short)(u >> 16);
}

__device__ __forceinline__ unsigned cvtpk(float lo, float hi) {
  unsigned r;
  asm("v_cvt_pk_bf16_f32 %0, %1, %2" : "=v"(r) : "v"(lo), "v"(hi));
  return r;
}

__device__ __forceinline__ int pswz(int s) { return ((s ^ (s >> 3)) & 7) << 4; }

// ---- kernel 1: convert + pre-swizzle weights to bf16 fragment order; W_q pre-scaled 0.125 ----
__global__ void wconv_kernel(const float* __restrict__ qw, const float* __restrict__ kw,
                             const float* __restrict__ vw, short* __restrict__ out) {
  int idx = blockIdx.x * 256 + threadIdx.x;
  int g = idx >> 15;
  int rem = idx & 32767;
  int lane = rem & 63;
  int n01 = (rem >> 6) & 1;
  int w   = (rem >> 7) & 15;
  int kk  = rem >> 11;
  int o  = w * 32 + n01 * 16 + (lane & 15);
  int k0 = kk * 32 + (lane >> 4) * 8;
  const float* src = (g == 0) ? qw : (g == 1) ? kw : vw;
  const float sc = (g == 0) ? 0.125f : 1.0f;
  const float* p = src + o * 512 + k0;
  float4v v0 = *(const float4v*)(p);
  float4v v1 = *(const float4v*)(p + 4);
  short8 o8;
  o8[0] = (short)f2bf(v0.x * sc); o8[1] = (short)f2bf(v0.y * sc);
  o8[2] = (short)f2bf(v0.z * sc); o8[3] = (short)f2bf(v0.w * sc);
  o8[4] = (short)f2bf(v1.x * sc); o8[5] = (short)f2bf(v1.y * sc);
  o8[6] = (short)f2bf(v1.z * sc); o8[7] = (short)f2bf(v1.w * sc);
  *(short8*)(out + idx * 8) = o8;
}

// ---- kernel 1b: expand relative-position bias to bexp[h][i][j], j padded to 56 ----
__global__ void bexp_kernel(const float* __restrict__ btab, float* __restrict__ bexp) {
  int idx = blockIdx.x * 256 + threadIdx.x;   // 86*256 = 22016 exactly
  float v = 0.f;
  if (idx < 21952) {
    int h = idx / 2744;
    int rem = idx - h * 2744;
    int i = rem / 56;
    int j = rem - i * 56;
    if (j < 49) {
      int yi = (i * 37) >> 8, xi = i - yi * 7;
      int yj = (j * 37) >> 8, xj = j - yj * 7;
      int t = (yi - yj + 6) * 13 + (xi - xj + 6);
      v = btab[t * 8 + h];
    }
  }
  bexp[idx] = v;
}

// ================== SPLIT kernel A: QKV projection (r13 GEMM verbatim) ==================
// 16 waves, LDS = XT only (57344 B incl. VT reuse) -> 2 blocks/CU co-resident (the
// point of the split: convoy gaps filled by sibling blocks). r18 qkv defects fixed:
// weights read ONCE (no mh split), depth-1/2 prefetch restored (r13 code), V written
// via in-LDS VT scatter (proven) + linear WIDE copy of the swizzled image to Vg.
// Q/K go to chunk-layout [bwi][s=392][64] (s = t*8+sg; r18-validated mapping).
__global__ __launch_bounds__(1024, 4) void qkv_kernel(
    const float* __restrict__ x, const short* __restrict__ wcvt,
    const float* __restrict__ qb, const float* __restrict__ kb, const float* __restrict__ vb,
    short* __restrict__ qg, short* __restrict__ kg, short* __restrict__ vg) {
  __shared__ __align__(16) char sm[57344];
  const int tid  = threadIdx.x;
  const int lane = tid & 63;
  const int wave = tid >> 6;       // 0..15
  const int bwi  = blockIdx.x;
  const int bb   = bwi >> 6, wi = bwi & 63;
  const int l15  = lane & 15;
  const int l4   = lane >> 4;
  const int ig   = l4 * 4;
  const int wcol = wave * 32;
  const int ckof = l4 * 16;

  // stage x tile -> XT bf16 [49][512], row-XOR swizzle
  {
    const float* xb = x + (size_t)bb * (3136 * 512);
    const int whi = (wi >> 3) * 7, wlo = (wi & 7) * 7;
    for (int idx = tid; idx < 49 * 128; idx += 1024) {
      int t = idx >> 7, c4 = idx & 127;
      int yt = (t * 37) >> 8, xt = t - yt * 7;
      int l = (whi + yt) * 56 + wlo + xt;
      float4v v = *(const float4v*)(xb + l * 512 + c4 * 4);
      uint2v o;
      o.x = cvtpk(v.x, v.y);
      o.y = cvtpk(v.z, v.w);
      int byte = t * 1024 + c4 * 8;
      *(uint2v*)(sm + (byte ^ ((t & 7) << 4))) = o;
    }
  }
  __syncthreads();

  int xbase[4], xsw[4];
#pragma unroll
  for (int mt = 0; mt < 4; ++mt) {
    int row = mt * 16 + l15;
    xbase[mt] = row * 1024;
    xsw[mt]   = (row & 7) << 4;
  }

  const short* wgb0 = wcvt + wave * 1024 + lane * 8;

#define LDWP(P, OFF) __builtin_bit_cast(bf16x8, *(const short8*)((P) + (OFF)))
#define LDX(MT, C) __builtin_bit_cast(bf16x8, *(const short8*)(sm + xbase[MT] + ((C) ^ xsw[MT])))

  // ---- pass 1: Q and K projections fused over ONE XT read stream ----
  {
    const short* wq = wgb0;
    const short* wk = wgb0 + 262144;
    float4v aq[2][4], ak[2][4];
#pragma unroll
    for (int nt = 0; nt < 2; ++nt)
#pragma unroll
      for (int mt = 0; mt < 4; ++mt) { aq[nt][mt] = (float4v)0.f; ak[nt][mt] = (float4v)0.f; }

    bf16x8 uq0 = LDWP(wq, 0), uq1 = LDWP(wq, 512);
    bf16x8 uk0 = LDWP(wk, 0), uk1 = LDWP(wk, 512);

#pragma unroll 1
    for (int kk = 0; kk < 16; ++kk) {
      const int nko = ((kk + 1) & 15) * 16384;
      bf16x8 nq0 = LDWP(wq, nko), nq1 = LDWP(wq, nko + 512);
      bf16x8 nk0 = LDWP(wk, nko), nk1 = LDWP(wk, nko + 512);
      const int c_ = kk * 64 + ckof;
      bf16x8 x0 = LDX(0, c_), x1 = LDX(1, c_), x2 = LDX(2, c_), x3 = LDX(3, c_);
      __builtin_amdgcn_s_setprio(1);
      aq[0][0] = __builtin_amdgcn_mfma_f32_16x16x32_bf16(uq0, x0, aq[0][0], 0, 0, 0);
      aq[1][0] = __builtin_amdgcn_mfma_f32_16x16x32_bf16(uq1, x0, aq[1][0], 0, 0, 0);
      ak[0][0] = __builtin_amdgcn_mfma_f32_16x16x32_bf16(uk0, x0, ak[0][0], 0, 0, 0);
      ak[1][0] = __builtin_amdgcn_mfma_f32_16x16x32_bf16(uk1, x0, ak[1][0], 0, 0, 0);
      aq[0][1] = __builtin_amdgcn_mfma_f32_16x16x32_bf16(uq0, x1, aq[0][1], 0, 0, 0);
      aq[1][1] = __builtin_amdgcn_mfma_f32_16x16x32_bf16(uq1, x1, aq[1][1], 0, 0, 0);
      ak[0][1] = __builtin_amdgcn_mfma_f32_16x16x32_bf16(uk0, x1, ak[0][1], 0, 0, 0);
      ak[1][1] = __builtin_amdgcn_mfma_f32_16x16x32_bf16(uk1, x1, ak[1][1], 0, 0, 0);
      aq[0][2] = __builtin_amdgcn_mfma_f32_16x16x32_bf16(uq0, x2, aq[0][2], 0, 0, 0);
      aq[1][2] = __builtin_amdgcn_mfma_f32_16x16x32_bf16(uq1, x2, aq[1][2], 0, 0, 0);
      ak[0][2] = __builtin_amdgcn_mfma_f32_16x16x32_bf16(uk0, x2, ak[0][2], 0, 0, 0);
      ak[1][2] = __builtin_amdgcn_mfma_f32_16x16x32_bf16(uk1, x2, ak[1][2], 0, 0, 0);
      aq[0][3] = __builtin_amdgcn_mfma_f32_16x16x32_bf16(uq0, x3, aq[0][3], 0, 0, 0);
      aq[1][3] = __builtin_amdgcn_mfma_f32_16x16x32_bf16(uq1, x3, aq[1][3], 0, 0, 0);
      ak[0][3] = __builtin_amdgcn_mfma_f32_16x16x32_bf16(uk0, x3, ak[0][3], 0, 0, 0);
      ak[1][3] = __builtin_amdgcn_mfma_f32_16x16x32_bf16(uk1, x3, ak[1][3], 0, 0, 0);
      __builtin_amdgcn_s_setprio(0);
      uq0 = nq0; uq1 = nq1; uk0 = nk0; uk1 = nk1;
    }

    // paired epilogue -> global chunk layout (row s = t*8+sg, 8-B stores)
#pragma unroll
    for (int nt = 0; nt < 2; ++nt) {
      int o0 = wcol + nt * 16 + ig;
      float4v bq = *(const float4v*)(qb + o0);
      float4v bk = *(const float4v*)(kb + o0);
#pragma unroll
      for (int r = 0; r < 4; ++r) bq[r] *= 0.125f;   // match pre-scaled W_q
      int dd0 = o0 & 63, sg = o0 >> 6;
#pragma unroll
      for (int mt = 0; mt < 4; ++mt) {
        int t = mt * 16 + l15;
        if (t < 49) {
          int s = t * 8 + sg;
          size_t off = ((size_t)bwi * 392 + s) * 64 + dd0;
          uint2v pq, pk;
          pq.x = cvtpk(aq[nt][mt][0] + bq[0], aq[nt][mt][1] + bq[1]);
          pq.y = cvtpk(aq[nt][mt][2] + bq[2], aq[nt][mt][3] + bq[3]);
          pk.x = cvtpk(ak[nt][mt][0] + bk[0], ak[nt][mt][1] + bk[1]);
          pk.y = cvtpk(ak[nt][mt][2] + bk[2], ak[nt][mt][3] + bk[3]);
          *(uint2v*)(qg + off) = pq;
          *(uint2v*)(kg + off) = pk;
        }
      }
    }
  }

  // ---- pass 2: V projection (depth-2 weight pipeline) -> LDS VT -> wide copy out ----
  {
    const short* wgb = wgb0 + 2 * 262144;
    float4v acc[2][4];
#pragma unroll
    for (int nt = 0; nt < 2; ++nt)
#pragma unroll
      for (int mt = 0; mt < 4; ++mt) acc[nt][mt] = (float4v)0.f;

    bf16x8 wa0 = LDWP(wgb, 0),     wa1 = LDWP(wgb, 512);
    bf16x8 wb0 = LDWP(wgb, 16384), wb1 = LDWP(wgb, 16384 + 512);
    bf16x8 wc0, wc1, wd0, wd1;

#define GEMM_PHASE(KIDX, W0, W1)                                                          \
    do {                                                                                  \
      const int c_ = (KIDX) * 64 + ckof;                                                  \
      bf16x8 x0_ = LDX(0, c_), x1_ = LDX(1, c_), x2_ = LDX(2, c_), x3_ = LDX(3, c_);      \
      __builtin_amdgcn_s_setprio(1);                                                      \
      acc[0][0] = __builtin_amdgcn_mfma_f32_16x16x32_bf16(W0, x0_, acc[0][0], 0, 0, 0);   \
      acc[1][0] = __builtin_amdgcn_mfma_f32_16x16x32_bf16(W1, x0_, acc[1][0], 0, 0, 0);   \
      acc[0][1] = __builtin_amdgcn_mfma_f32_16x16x32_bf16(W0, x1_, acc[0][1], 0, 0, 0);   \
      acc[1][1] = __builtin_amdgcn_mfma_f32_16x16x32_bf16(W1, x1_, acc[1][1], 0, 0, 0);   \
      acc[0][2] = __builtin_amdgcn_mfma_f32_16x16x32_bf16(W0, x2_, acc[0][2], 0, 0, 0);   \
      acc[1][2] = __builtin_amdgcn_mfma_f32_16x16x32_bf16(W1, x2_, acc[1][2], 0, 0, 0);   \
      acc[0][3] = __builtin_amdgcn_mfma_f32_16x16x32_bf16(W0, x3_, acc[0][3], 0, 0, 0);   \
      acc[1][3] = __builtin_amdgcn_mfma_f32_16x16x32_bf16(W1, x3_, acc[1][3], 0, 0, 0);   \
      __builtin_amdgcn_s_setprio(0);                                                      \
    } while (0)

#pragma unroll 1
    for (int kk = 0; kk < 16; kk += 4) {
      wc0 = LDWP(wgb, ((kk + 2) & 15) * 16384); wc1 = LDWP(wgb, ((kk + 2) & 15) * 16384 + 512);
      GEMM_PHASE(kk, wa0, wa1);
      wd0 = LDWP(wgb, ((kk + 3) & 15) * 16384); wd1 = LDWP(wgb, ((kk + 3) & 15) * 16384 + 512);
      GEMM_PHASE(kk + 1, wb0, wb1);
      wa0 = LDWP(wgb, ((kk + 4) & 15) * 16384); wa1 = LDWP(wgb, ((kk + 4) & 15) * 16384 + 512);
      GEMM_PHASE(kk + 2, wc0, wc1);
      wb0 = LDWP(wgb, ((kk + 5) & 15) * 16384); wb1 = LDWP(wgb, ((kk + 5) & 15) * 16384 + 512);
      GEMM_PHASE(kk + 3, wd0, wd1);
    }
#undef GEMM_PHASE

    __syncthreads();  // all waves done reading XT; region A becomes VT [dd][h2*56+tp]
#pragma unroll
    for (int nt = 0; nt < 2; ++nt) {
      int o0 = wcol + nt * 16 + ig;
      float4v bv = *(const float4v*)(vb + o0);
      int dd0 = o0 & 63, sg = o0 >> 6;
#pragma unroll
      for (int mt = 0; mt < 4; ++mt) {
        int t = mt * 16 + l15;
        if (t < 49) {
          int s = t * 8 + sg;
          int h2 = (s * 1339) >> 16;       // s / 49 (destination head stripe)
          int colb = h2 * 112 + (s - h2 * 49) * 2;
#pragma unroll
          for (int r = 0; r < 4; ++r) {
            int dd = dd0 + r;
            *(unsigned short*)(sm + ((dd * 896 + colb) ^ ((dd & 7) << 4))) =
                f2bf(acc[nt][mt][r] + bv[r]);
          }
        }
      }
    }
    // zero VT junk cols tp=49..55 (r9 lesson: 0*NaN=NaN in PV)
    for (int idx = tid; idx < 3584; idx += 1024) {
      int q = idx >> 9;
      int rem = idx & 511;
      int h2 = rem >> 6, dd = rem & 63;
      *(unsigned short*)(sm + ((dd * 896 + h2 * 112 + (49 + q) * 2) ^ ((dd & 7) << 4))) = 0;
    }
    __syncthreads();  // VT image complete

    // wide copy of the swizzled VT image -> Vg[bwi] (attn2 reads with same XOR)
    {
      const short4v* src = (const short4v*)sm;
      short4v* dst = (short4v*)(vg + (size_t)bwi * 28672);
      for (int i = tid; i < 7168; i += 1024) dst[i] = src[i];
    }
    if (bwi == 1023) {   // zero tail pad (attn2 dd=63,h=7,tp0=56 over-read lands here)
      short* pad = vg + (size_t)1024 * 28672;
      for (int i = tid; i < 2048; i += 1024) pad[i] = 0;
    }
  }
#undef LDWP
#undef LDX
}

// ================== SPLIT kernel B: per-(window,head) attention ==================
// 4 independent waves/block, each owns one (bwi,h). Q/K chunk rows s = h*49+i of
// [bwi][392][64] (r18-validated). V read from the per-window swizzled VT image with
// the fused kernel's exact XOR addressing -> PV path bit-identical to proven fused.
__global__ __launch_bounds__(256, 4) void attn2_kernel(
    const short* __restrict__ qg, const short* __restrict__ kg, const short* __restrict__ vg,
    const float* __restrict__ bexp, float* __restrict__ out) {
  __shared__ __align__(16) char ovs[4][8192];
  const int tid  = threadIdx.x;
  const int lane = tid & 63;
  const int wave = tid >> 6;
  const int bh   = blockIdx.x * 4 + wave;   // [0, 8192)
  const int h    = bh & 7, bwi = bh >> 3;
  const int l15  = lane & 15;
  const int l4   = lane >> 4;
  const int ig   = l4 * 4;
  char* ov = ovs[wave];

  const short* Qh = qg + ((size_t)bwi * 392 + h * 49) * 64;
  const short* Kh = kg + ((size_t)bwi * 392 + h * 49) * 64;
  const char*  Vw = (const char*)(vg + (size_t)bwi * 28672);

  float4v scr[4][4];
#pragma unroll
  for (int jt = 0; jt < 4; ++jt)
#pragma unroll
    for (int it = 0; it < 4; ++it) scr[jt][it] = (float4v)0.f;

#pragma unroll
  for (int ks = 0; ks < 2; ++ks) {
    const int dd = ks * 32 + l4 * 8;
    bf16x8 kf[4], qf[4];
#pragma unroll
    for (int jt = 0; jt < 4; ++jt)   // rows >=49: neighboring chunks, masked by index
      kf[jt] = __builtin_bit_cast(bf16x8, *(const short8*)(Kh + (size_t)(jt * 16 + l15) * 64 + dd));
#pragma unroll
    for (int it = 0; it < 4; ++it)
      qf[it] = __builtin_bit_cast(bf16x8, *(const short8*)(Qh + (size_t)(it * 16 + l15) * 64 + dd));
    __builtin_amdgcn_s_setprio(1);
#pragma unroll
    for (int jt = 0; jt < 4; ++jt)
#pragma unroll
      for (int it = 0; it < 4; ++it)
        scr[jt][it] = __builtin_amdgcn_mfma_f32_16x16x32_bf16(kf[jt], qf[it], scr[jt][it], 0, 0, 0);
    __builtin_amdgcn_s_setprio(0);
  }

  const float* bx = bexp + h * 2744;
#pragma unroll
  for (int it = 0; it < 4; ++it) {
    int i = it * 16 + l15;
    const float* bi = bx + ((i > 48) ? 48 : i) * 56 + ig;
    float mx = -1e30f;
#pragma unroll
    for (int jt = 0; jt < 4; ++jt) {
      float4v b4 = *(const float4v*)(bi + jt * 16);
#pragma unroll
      for (int r = 0; r < 4; ++r) {
        int j = jt * 16 + ig + r;
        float v = (i < 49 && j < 49) ? scr[jt][it][r] + b4[r] : -1e30f;
        scr[jt][it][r] = v;
        mx = fmaxf(mx, v);
      }
    }
    mx = fmaxf(mx, __shfl_xor(mx, 16));
    mx = fmaxf(mx, __shfl_xor(mx, 32));
    float ssum = 0.f;
#pragma unroll
    for (int jt = 0; jt < 4; ++jt)
#pragma unroll
      for (int r = 0; r < 4; ++r) {
        float e = __expf(scr[jt][it][r] - mx);
        scr[jt][it][r] = e;
        ssum += e;
      }
    ssum += __shfl_xor(ssum, 16);
    ssum += __shfl_xor(ssum, 32);
    float inv = 1.f / ssum;
#pragma unroll
    for (int jt = 0; jt < 4; ++jt)
#pragma unroll
      for (int r = 0; r < 4; ++r) scr[jt][it][r] *= inv;
  }

#pragma unroll
  for (int it = 0; it < 4; ++it) {
    int i = it * 16 + l15;
    if (i < 49) {
      int rowb = i * 128, swz = (i & 7) << 4;
#pragma unroll
      for (int jt = 0; jt < 4; ++jt) {
        uint2v p2;
        p2.x = cvtpk(scr[jt][it][0], scr[jt][it][1]);
        p2.y = cvtpk(scr[jt][it][2], scr[jt][it][3]);
        *(uint2v*)(ov + ((rowb + jt * 32 + ig * 2) ^ swz)) = p2;
      }
    }
  }
  __syncthreads();

  float4v oacc[4][4];
#pragma unroll
  for (int dt = 0; dt < 4; ++dt)
#pragma unroll
    for (int tt = 0; tt < 4; ++tt) oacc[dt][tt] = (float4v)0.f;

#pragma unroll
  for (int ks = 0; ks < 2; ++ks) {
    const int tp0 = ks * 32 + l4 * 8;   // tp 49..55 zeroed; tp0=56 over-read: finite
    bf16x8 vf[4], af[4];
#pragma unroll
    for (int dt = 0; dt < 4; ++dt) {
      int dd = dt * 16 + l15;
      int off = (dd * 896 + h * 112 + tp0 * 2) ^ ((dd & 7) << 4);
      vf[dt] = __builtin_bit_cast(bf16x8, *(const short8*)(Vw + off));
    }
#pragma unroll
    for (int tt = 0; tt < 4; ++tt) {
      int t = tt * 16 + l15;
      int tr = (t > 48) ? 48 : t;
      af[tt] = __builtin_bit_cast(bf16x8,
          *(const short8*)(ov + ((tr * 128 + tp0 * 2) ^ ((tr & 7) << 4))));
    }
    __builtin_amdgcn_s_setprio(1);
#pragma unroll
    for (int dt = 0; dt < 4; ++dt)
#pragma unroll
      for (int tt = 0; tt < 4; ++tt)
        oacc[dt][tt] = __builtin_amdgcn_mfma_f32_16x16x32_bf16(vf[dt], af[tt], oacc[dt][tt], 0, 0, 0);
    __builtin_amdgcn_s_setprio(0);
  }

  float* op = out + (size_t)bwi * 25088 + h * 3136;
#pragma unroll
  for (int tt = 0; tt < 4; ++tt) {
    int t = tt * 16 + l15;
    if (t < 49) {
#pragma unroll
      for (int dt = 0; dt < 4; ++dt)
        *(float4v*)(op + t * 64 + dt * 16 + ig) = oacc[dt][tt];
    }
  }
}

// ================== FALLBACK: r16 fused kernel (147 us floor) ==================
__global__ __launch_bounds__(1024, 4) void wattn_kernel(
    const float* __restrict__ x, const short* __restrict__ wcvt,
    const float* __restrict__ qb, const float* __restrict__ kb, const float* __restrict__ vb,
    const float* __restrict__ bexp, float* __restrict__ out) {
  __shared__ __align__(16) char sm[LDS_TOTAL];
  const int tid  = threadIdx.x;
  const int lane = tid & 63;
  const int wave = tid >> 6;
  const int bwi  = blockIdx.x;
  const int bb   = bwi >> 6, wi = bwi & 63;
  const int l15  = lane & 15;
  const int l4   = lane >> 4;
  const int ig   = l4 * 4;
  const int wcol = wave * 32;
  const int ckof = l4 * 16;
  const int h    = wave & 7;
  const int mh   = wave >> 3;

  {
    const float* xb = x + (size_t)bb * (3136 * 512);
    const int whi = (wi >> 3) * 7, wlo = (wi & 7) * 7;
    for (int idx = tid; idx < 49 * 128; idx += 1024) {
      int t = idx >> 7, c4 = idx & 127;
      int yt = (t * 37) >> 8, xt = t - yt * 7;
      int l = (whi + yt) * 56 + wlo + xt;
      float4v v = *(const float4v*)(xb + l * 512 + c4 * 4);
      uint2v o;
      o.x = cvtpk(v.x, v.y);
      o.y = cvtpk(v.z, v.w);
      int byte = t * 1024 + c4 * 8;
      *(uint2v*)(sm + (byte ^ ((t & 7) << 4))) = o;
    }
  }
  __syncthreads();

  int xbase[4], xsw[4];
#pragma unroll
  for (int mt = 0; mt < 4; ++mt) {
    int row = mt * 16 + l15;
    xbase[mt] = row * 1024;
    xsw[mt]   = (row & 7) << 4;
  }

  const short* wgb0 = wcvt + wave * 1024 + lane * 8;

#define LDWP(P, OFF) __builtin_bit_cast(bf16x8, *(const short8*)((P) + (OFF)))
#define LDX(MT, C) __builtin_bit_cast(bf16x8, *(const short8*)(sm + xbase[MT] + ((C) ^ xsw[MT])))

  {
    const short* wq = wgb0;
    const short* wk = wgb0 + 262144;
    float4v aq[2][4], ak[2][4];
#pragma unroll
    for (int nt = 0; nt < 2; ++nt)
#pragma unroll
      for (int mt = 0; mt < 4; ++mt) { aq[nt][mt] = (float4v)0.f; ak[nt][mt] = (float4v)0.f; }

    bf16x8 uq0 = LDWP(wq, 0), uq1 = LDWP(wq, 512);
    bf16x8 uk0 = LDWP(wk, 0), uk1 = LDWP(wk, 512);

#pragma unroll 1
    for (int kk = 0; kk < 16; ++kk) {
      const int nko = ((kk + 1) & 15) * 16384;
      bf16x8 nq0 = LDWP(wq, nko), nq1 = LDWP(wq, nko + 512);
      bf16x8 nk0 = LDWP(wk, nko), nk1 = LDWP(wk, nko + 512);
      const int c_ = kk * 64 + ckof;
      bf16x8 x0 = LDX(0, c_), x1 = LDX(1, c_), x2 = LDX(2, c_), x3 = LDX(3, c_);
      __builtin_amdgcn_s_setprio(1);
      aq[0][0] = __builtin_amdgcn_mfma_f32_16x16x32_bf16(uq0, x0, aq[0][0], 0, 0, 0);
      aq[1][0] = __builtin_amdgcn_mfma_f32_16x16x32_bf16(uq1, x0, aq[1][0], 0, 0, 0);
      ak[0][0] = __builtin_amdgcn_mfma_f32_16x16x32_bf16(uk0, x0, ak[0][0], 0, 0, 0);
      ak[1][0] = __builtin_amdgcn_mfma_f32_16x16x32_bf16(uk1, x0, ak[1][0], 0, 0, 0);
      aq[0][1] = __builtin_amdgcn_mfma_f32_16x16x32_bf16(uq0, x1, aq[0][1], 0, 0, 0);
      aq[1][1] = __builtin_amdgcn_mfma_f32_16x16x32_bf16(uq1, x1, aq[1][1], 0, 0, 0);
      ak[0][1] = __builtin_amdgcn_mfma_f32_16x16x32_bf16(uk0, x1, ak[0][1], 0, 0, 0);
      ak[1][1] = __builtin_amdgcn_mfma_f32_16x16x32_bf16(uk1, x1, ak[1][1], 0, 0, 0);
      aq[0][2] = __builtin_amdgcn_mfma_f32_16x16x32_bf16(uq0, x2, aq[0][2], 0, 0, 0);
      aq[1][2] = __builtin_amdgcn_mfma_f32_16x16x32_bf16(uq1, x2, aq[1][2], 0, 0, 0);
      ak[0][2] = __builtin_amdgcn_mfma_f32_16x16x32_bf16(uk0, x2, ak[0][2], 0, 0, 0);
      ak[1][2] = __builtin_amdgcn_mfma_f32_16x16x32_bf16(uk1, x2, ak[1][2], 0, 0, 0);
      aq[0][3] = __builtin_amdgcn_mfma_f32_16x16x32_bf16(uq0, x3, aq[0][3], 0, 0, 0);
      aq[1][3] = __builtin_amdgcn_mfma_f32_16x16x32_bf16(uq1, x3, aq[1][3], 0, 0, 0);
      ak[0][3] = __builtin_amdgcn_mfma_f32_16x16x32_bf16(uk0, x3, ak[0][3], 0, 0, 0);
      ak[1][3] = __builtin_amdgcn_mfma_f32_16x16x32_bf16(uk1, x3, ak[1][3], 0, 0, 0);
      __builtin_amdgcn_s_setprio(0);
      uq0 = nq0; uq1 = nq1; uk0 = nk0; uk1 = nk1;
    }

#pragma unroll
    for (int nt = 0; nt < 2; ++nt) {
      int o0 = wcol + nt * 16 + ig;
      float4v bq = *(const float4v*)(qb + o0);
      float4v bk = *(const float4v*)(kb + o0);
#pragma unroll
      for (int r = 0; r < 4; ++r) bq[r] *= 0.125f;
      int dd0 = o0 & 63, sg = o0 >> 6;
#pragma unroll
      for (int mt = 0; mt < 4; ++mt) {
        int t = mt * 16 + l15;
        if (t < 49) {
          int s = t * 8 + sg;
          int addr = (s * 128 + dd0 * 2) ^ pswz(s);
          uint2v pq, pk;
          pq.x = cvtpk(aq[nt][mt][0] + bq[0], aq[nt][mt][1] + bq[1]);
          pq.y = cvtpk(aq[nt][mt][2] + bq[2], aq[nt][mt][3] + bq[3]);
          pk.x = cvtpk(ak[nt][mt][0] + bk[0], ak[nt][mt][1] + bk[1]);
          pk.y = cvtpk(ak[nt][mt][2] + bk[2], ak[nt][mt][3] + bk[3]);
          *(uint2v*)(sm + LDS_PQ + addr) = pq;
          *(uint2v*)(sm + LDS_PK + addr) = pk;
        }
      }
    }
  }

  float4v acc[2][4];
  {
    const short* wgb = wgb0 + 2 * 262144;
#pragma unroll
    for (int nt = 0; nt < 2; ++nt)
#pragma unroll
      for (int mt = 0; mt < 4; ++mt) acc[nt][mt] = (float4v)0.f;

    bf16x8 wa0 = LDWP(wgb, 0),     wa1 = LDWP(wgb, 512);
    bf16x8 wb0 = LDWP(wgb, 16384), wb1 = LDWP(wgb, 16384 + 512);
    bf16x8 wc0, wc1, wd0, wd1;

#define GEMM_PHASE(KIDX, W0, W1)                                                          \
    do {                                                                                  \
      const int c_ = (KIDX) * 64 + ckof;                                                  \
      bf16x8 x0_ = LDX(0, c_), x1_ = LDX(1, c_), x2_ = LDX(2, c_), x3_ = LDX(3, c_);      \
      __builtin_amdgcn_s_setprio(1);                                                      \
      acc[0][0] = __builtin_amdgcn_mfma_f32_16x16x32_bf16(W0, x0_, acc[0][0], 0, 0, 0);   \
      acc[1][0] = __builtin_amdgcn_mfma_f32_16x16x32_bf16(W1, x0_, acc[1][0], 0, 0, 0);   \
      acc[0][1] = __builtin_amdgcn_mfma_f32_16x16x32_bf16(W0, x1_, acc[0][1], 0, 0, 0);   \
      acc[1][1] = __builtin_amdgcn_mfma_f32_16x16x32_bf16(W1, x1_, acc[1][1], 0, 0, 0);   \
      acc[0][2] = __builtin_amdgcn_mfma_f32_16x16x32_bf16(W0, x2_, acc[0][2], 0, 0, 0);   \
      acc[1][2] = __builtin_amdgcn_mfma_f32_16x16x32_bf16(W1, x2_, acc[1][2], 0, 0, 0);   \
      acc[0][3] = __builtin_amdgcn_mfma_f32_16x16x32_bf16(W0, x3_, acc[0][3], 0, 0, 0);   \
      acc[1][3] = __builtin_amdgcn_mfma_f32_16x16x32_bf16(W1, x3_, acc[1][3], 0, 0, 0);   \
      __builtin_amdgcn_s_setprio(0);                                                      \
    } while (0)

#pragma unroll 1
    for (int kk = 0; kk < 16; kk += 4) {
      wc0 = LDWP(wgb, ((kk + 2) & 15) * 16384); wc1 = LDWP(wgb, ((kk + 2) & 15) * 16384 + 512);
      GEMM_PHASE(kk, wa0, wa1);
      wd0 = LDWP(wgb, ((kk + 3) & 15) * 16384); wd1 = LDWP(wgb, ((kk + 3) & 15) * 16384 + 512);
      GEMM_PHASE(kk + 1, wb0, wb1);
      wa0 = LDWP(wgb, ((kk + 4) & 15) * 16384); wa1 = LDWP(wgb, ((kk + 4) & 15) * 16384 + 512);
      GEMM_PHASE(kk + 2, wc0, wc1);
      wb0 = LDWP(wgb, ((kk + 5) & 15) * 16384); wb1 = LDWP(wgb, ((kk + 5) & 15) * 16384 + 512);
      GEMM_PHASE(kk + 3, wd0, wd1);
    }
#undef GEMM_PHASE
  }

  __syncthreads();

  float4v scr[4][2];
#pragma unroll
  for (int jt = 0; jt < 4; ++jt)
#pragma unroll
    for (int it = 0; it < 2; ++it) scr[jt][it] = (float4v)0.f;

#pragma unroll
  for (int ks = 0; ks < 2; ++ks) {
    const int dd = ks * 32 + l4 * 8;
    bf16x8 kf[4], qf[2];
#pragma unroll
    for (int jt = 0; jt < 4; ++jt) {
      int s = h * 49 + jt * 16 + l15;
      int flat = s * 128 + dd * 2;
      kf[jt] = __builtin_bit_cast(bf16x8, *(const short8*)(sm + LDS_PK + (flat ^ pswz(s))));
    }
#pragma unroll
    for (int it = 0; it < 2; ++it) {
      int s = h * 49 + (mh * 2 + it) * 16 + l15;
      int flat = s * 128 + dd * 2;
      qf[it] = __builtin_bit_cast(bf16x8, *(const short8*)(sm + LDS_PQ + (flat ^ pswz(s))));
    }
    __builtin_amdgcn_s_setprio(1);
#pragma unroll
    for (int jt = 0; jt < 4; ++jt)
#pragma unroll
      for (int it = 0; it < 2; ++it)
        scr[jt][it] = __builtin_amdgcn_mfma_f32_16x16x32_bf16(kf[jt], qf[it], scr[jt][it], 0, 0, 0);
    __builtin_amdgcn_s_setprio(0);
  }

  {
#pragma unroll
    for (int nt = 0; nt < 2; ++nt) {
      int o0 = wcol + nt * 16 + ig;
      float4v bv = *(const float4v*)(vb + o0);
      int dd0 = o0 & 63, sg = o0 >> 6;
#pragma unroll
      for (int mt = 0; mt < 4; ++mt) {
        int t = mt * 16 + l15;
        if (t < 49) {
          int s = t * 8 + sg;
          int h2 = (s * 1339) >> 16;
          int colb = h2 * 112 + (s - h2 * 49) * 2;
#pragma unroll
          for (int r = 0; r < 4; ++r) {
            int dd = dd0 + r;
            *(unsigned short*)(sm + ((dd * 896 + colb) ^ ((dd & 7) << 4))) =
                f2bf(acc[nt][mt][r] + bv[r]);
          }
        }
      }
    }
    for (int idx = tid; idx < 3584; idx += 1024) {
      int q = idx >> 9;
      int rem = idx & 511;
      int h2 = rem >> 6, dd = rem & 63;
      *(unsigned short*)(sm + ((dd * 896 + h2 * 112 + (49 + q) * 2) ^ ((dd & 7) << 4))) = 0;
    }
  }

  const float* bx = bexp + h * 2744;
#pragma unroll
  for (int it = 0; it < 2; ++it) {
    int i = (mh * 2 + it) * 16 + l15;
    const float* bi = bx + ((i > 48) ? 48 : i) * 56 + ig;
    float mx = -1e30f;
#pragma unroll
    for (int jt = 0; jt < 4; ++jt) {
      float4v b4 = *(const float4v*)(bi + jt * 16);
#pragma unroll
      for (int r = 0; r < 4; ++r) {
        int j = jt * 16 + ig + r;
        float v = (i < 49 && j < 49) ? scr[jt][it][r] + b4[r] : -1e30f;
        scr[jt][it][r] = v;
        mx = fmaxf(mx, v);
      }
    }
    mx = fmaxf(mx, __shfl_xor(mx, 16));
    mx = fmaxf(mx, __shfl_xor(mx, 32));
    float ssum = 0.f;
#pragma unroll
    for (int jt = 0; jt < 4; ++jt)
#pragma unroll
      for (int r = 0; r < 4; ++r) {
        float e = __expf(scr[jt][it][r] - mx);
        scr[jt][it][r] = e;
        ssum += e;
      }
    ssum += __shfl_xor(ssum, 16);
    ssum += __shfl_xor(ssum, 32);
    float inv = 1.f / ssum;
#pragma unroll
    for (int jt = 0; jt < 4; ++jt)
#pragma unroll
      for (int r = 0; r < 4; ++r) scr[jt][it][r] *= inv;
  }

#pragma unroll
  for (int it = 0; it < 2; ++it) {
    int i = (mh * 2 + it) * 16 + l15;
    if (i < 49) {
      int s = h * 49 + i;
      int rowb = s * 128;
      int swz = pswz(s);
#pragma unroll
      for (int jt = 0; jt < 4; ++jt) {
        uint2v pk2;
        pk2.x = cvtpk(scr[jt][it][0], scr[jt][it][1]);
        pk2.y = cvtpk(scr[jt][it][2], scr[jt][it][3]);
        *(uint2v*)(sm + LDS_PQ + ((rowb + jt * 32 + ig * 2) ^ swz)) = pk2;
      }
    }
  }

  __syncthreads();

  float4v oacc[4][2];
#pragma unroll
  for (int dt = 0; dt < 4; ++dt)
#pragma unroll
    for (int tt = 0; tt < 2; ++tt) oacc[dt][tt] = (float4v)0.f;

#pragma unroll
  for (int ks = 0; ks < 2; ++ks) {
    const int tp0 = ks * 32 + l4 * 8;
    bf16x8 vf[4], af[2];
#pragma unroll
    for (int dt = 0; dt < 4; ++dt) {
      int dd = dt * 16 + l15;
      vf[dt] = __builtin_bit_cast(bf16x8,
          *(const short8*)(sm + ((dd * 896 + h * 112 + tp0 * 2) ^ ((dd & 7) << 4))));
    }
#pragma unroll
    for (int tt = 0; tt < 2; ++tt) {
      int t = (mh * 2 + tt) * 16 + l15;
      int tr = (t > 48) ? 48 : t;
      int s = h * 49 + tr;
      af[tt] = __builtin_bit_cast(bf16x8,
          *(const short8*)(sm + LDS_PQ + ((s * 128 + tp0 * 2) ^ pswz(s))));
    }
    __builtin_amdgcn_s_setprio(1);
#pragma unroll
    for (int dt = 0; dt < 4; ++dt)
#pragma unroll
      for (int tt = 0; tt < 2; ++tt)
        oacc[dt][tt] = __builtin_amdgcn_mfma_f32_16x16x32_bf16(vf[dt], af[tt], oacc[dt][tt], 0, 0, 0);
    __builtin_amdgcn_s_setprio(0);
  }

  float* op = out + (size_t)bwi * 25088 + h * 3136;
#pragma unroll
  for (int tt = 0; tt < 2; ++tt) {
    int t = (mh * 2 + tt) * 16 + l15;
    if (t < 49) {
#pragma unroll
      for (int dt = 0; dt < 4; ++dt)
        *(float4v*)(op + t * 64 + dt * 16 + ig) = oacc[dt][tt];
    }
  }
#undef LDWP
#undef LDX
}

extern "C" void kernel_launch(void* const* d_in, const int* in_sizes, int n_in,
                              void* d_out, int out_size, void* d_ws, size_t ws_size,
                              hipStream_t stream) {
  const float* x    = (const float*)d_in[0];
  const float* q_w  = (const float*)d_in[1];
  const float* q_b  = (const float*)d_in[2];
  const float* k_w  = (const float*)d_in[3];
  const float* k_b  = (const float*)d_in[4];
  const float* v_w  = (const float*)d_in[5];
  const float* v_b  = (const float*)d_in[6];
  const float* btab = (const float*)d_in[7];
  short* wcvt = (short*)d_ws;                              // 1.5 MB fragment-order weights
  float* bexp = (float*)((char*)d_ws + 3 * 262144 * 2);    // 22016 f32 bias table

  hipLaunchKernelGGL(wconv_kernel, dim3(384), dim3(256), 0, stream, q_w, k_w, v_w, wcvt);
  hipLaunchKernelGGL(bexp_kernel, dim3(86), dim3(256), 0, stream, btab, bexp);

  // split path: Qg/Kg = 1024*392*64 bf16 (51.38 MB each, +4K overrun pad),
  // Vg = 1024 swizzled 57344-B VT images (58.72 MB, +4K pad)
  const size_t QG_OFF = 2097152;
  const size_t KG_OFF = QG_OFF + 51380224 + 4096;          // 53,481,472
  const size_t VG_OFF = KG_OFF + 51380224 + 4096;          // 104,865,792
  const size_t REQUIRED = VG_OFF + 58720256 + 4096;        // 163,590,144
  if (ws_size >= REQUIRED) {
    short* qg = (short*)((char*)d_ws + QG_OFF);
    short* kg = (short*)((char*)d_ws + KG_OFF);
    short* vg = (short*)((char*)d_ws + VG_OFF);
    hipLaunchKernelGGL(qkv_kernel, dim3(1024), dim3(1024), 0, stream,
                       x, wcvt, q_b, k_b, v_b, qg, kg, vg);
    hipLaunchKernelGGL(attn2_kernel, dim3(2048), dim3(256), 0, stream,
                       qg, kg, vg, bexp, (float*)d_out);
  } else {
    hipLaunchKernelGGL(wattn_kernel, dim3(1024), dim3(1024), 0, stream,
                       x, wcvt, q_b, k_b, v_b, bexp, (float*)d_out);
  }
}

// Round 20
// 145.783 us; speedup vs baseline: 1.7983x; 1.3711x over previous
//
#include <hip/hip_runtime.h>

typedef __attribute__((ext_vector_type(8))) short short8;
typedef __attribute__((ext_vector_type(4))) short short4v;
typedef __attribute__((ext_vector_type(4))) float float4v;
typedef __attribute__((ext_vector_type(2))) unsigned int uint2v;
typedef __attribute__((ext_vector_type(8))) __bf16 bf16x8;

// LDS layout (bytes):
//   region A  [0, 57344)        : XT bf16[49][512] (row-XOR swz) during GEMMs;
//                                 VT bf16[64][448] (= [dd][h*56+tp], XOR (dd&7)<<4) after V
//   PQ        [57344, 107520)   : P_q bf16, row s=8t+sg at s*128 (pswz). After softmax the
//                                 (h,mh) wave OVERLAYS attn in place into rows s=h*49+i.
//   PK        [107520, 157696)  : P_k same layout
#define LDS_PQ 57344
#define LDS_PK 107520
#define LDS_TOTAL 157696

__device__ __forceinline__ unsigned short f2bf(float f) {
  unsigned u = __float_as_uint(f);
  u += 0x7FFFu + ((u >> 16) & 1u);   // RNE
  return (unsigned short)(u >> 16);
}

// hardware packed f32->bf16 (RNE), 1 instr for 2 elements; no builtin on gfx950
__device__ __forceinline__ unsigned cvtpk(float lo, float hi) {
  unsigned r;
  asm("v_cvt_pk_bf16_f32 %0, %1, %2" : "=v"(r) : "v"(lo), "v"(hi));
  return r;
}

// P-region swizzle: store lanes vary t (s>>3), read lanes vary s -> both spread.
__device__ __forceinline__ int pswz(int s) { return ((s ^ (s >> 3)) & 7) << 4; }

// ---- kernel 1: convert + pre-swizzle q_w/k_w/v_w fp32 -> bf16 fragment order ----
// [g][kk=16][wave=16][n01=2][lane=64][j=8] shorts. W_q is PRE-SCALED by 0.125
// (exact power-of-2: identical mantissas) so the QK^T scale is folded away.
// Element = W_g[o = w*32 + n01*16 + (lane&15)][k = kk*32 + (lane>>4)*8 + j]
__global__ void wconv_kernel(const float* __restrict__ qw, const float* __restrict__ kw,
                             const float* __restrict__ vw, short* __restrict__ out) {
  int idx = blockIdx.x * 256 + threadIdx.x;   // 3*32768 threads, 8 shorts each
  int g = idx >> 15;
  int rem = idx & 32767;
  int lane = rem & 63;
  int n01 = (rem >> 6) & 1;
  int w   = (rem >> 7) & 15;
  int kk  = rem >> 11;
  int o  = w * 32 + n01 * 16 + (lane & 15);
  int k0 = kk * 32 + (lane >> 4) * 8;
  const float* src = (g == 0) ? qw : (g == 1) ? kw : vw;
  const float sc = (g == 0) ? 0.125f : 1.0f;
  const float* p = src + o * 512 + k0;
  float4v v0 = *(const float4v*)(p);
  float4v v1 = *(const float4v*)(p + 4);
  short8 o8;
  o8[0] = (short)f2bf(v0.x * sc); o8[1] = (short)f2bf(v0.y * sc);
  o8[2] = (short)f2bf(v0.z * sc); o8[3] = (short)f2bf(v0.w * sc);
  o8[4] = (short)f2bf(v1.x * sc); o8[5] = (short)f2bf(v1.y * sc);
  o8[6] = (short)f2bf(v1.z * sc); o8[7] = (short)f2bf(v1.w * sc);
  *(short8*)(out + idx * 8) = o8;
}

// ---- kernel 1b: expand relative-position bias to bexp[h][i][j], j padded to 56 ----
__global__ void bexp_kernel(const float* __restrict__ btab, float* __restrict__ bexp) {
  int idx = blockIdx.x * 256 + threadIdx.x;   // 86*256 = 22016 exactly
  float v = 0.f;
  if (idx < 21952) {
    int h = idx / 2744;
    int rem = idx - h * 2744;
    int i = rem / 56;
    int j = rem - i * 56;
    if (j < 49) {
      int yi = (i * 37) >> 8, xi = i - yi * 7;
      int yj = (j * 37) >> 8, xj = j - yj * 7;
      int t = (yi - yj + 6) * 13 + (xi - xj + 6);
      v = btab[t * 8 + h];
    }
  }
  bexp[idx] = v;
}

// ---- kernel 2: fused windowed attention, one 1024-thread workgroup per (b, window) ----
// FINAL (best measured 146.9 us, r15). 16 waves, 1 block/CU (LDS-capped).
// Validated laws: (r3/r5/r14) ANY live-range growth at the 128-reg cap spills ->
// rolled loops, no pipeline copies, no persistent outer loop; (r8) fragment-order
// coalesced weights; (r11) no redundant weight streams; (r12/r13) LDS is the
// dominant per-CU pipe -> Q+K fused over one X pass; (r19) attention is fully
// hidden in GEMM convoy gaps -- splitting it out only adds an HBM round-trip.
__global__ __launch_bounds__(1024, 4) void wattn_kernel(
    const float* __restrict__ x, const short* __restrict__ wcvt,
    const float* __restrict__ qb, const float* __restrict__ kb, const float* __restrict__ vb,
    const float* __restrict__ bexp, float* __restrict__ out) {
  __shared__ __align__(16) char sm[LDS_TOTAL];
  const int tid  = threadIdx.x;
  const int lane = tid & 63;
  const int wave = tid >> 6;       // 0..15
  const int bwi  = blockIdx.x;     // b*64 + wi
  const int bb   = bwi >> 6, wi = bwi & 63;
  const int l15  = lane & 15;
  const int l4   = lane >> 4;
  const int ig   = l4 * 4;
  const int wcol = wave * 32;
  const int ckof = l4 * 16;
  const int h    = wave & 7;
  const int mh   = wave >> 3;

  // stage x tile -> XT bf16 [49][512], row-XOR swizzle
  {
    const float* xb = x + (size_t)bb * (3136 * 512);
    const int whi = (wi >> 3) * 7, wlo = (wi & 7) * 7;
    for (int idx = tid; idx < 49 * 128; idx += 1024) {
      int t = idx >> 7, c4 = idx & 127;
      int yt = (t * 37) >> 8, xt = t - yt * 7;
      int l = (whi + yt) * 56 + wlo + xt;
      float4v v = *(const float4v*)(xb + l * 512 + c4 * 4);
      uint2v o;
      o.x = cvtpk(v.x, v.y);
      o.y = cvtpk(v.z, v.w);
      int byte = t * 1024 + c4 * 8;
      *(uint2v*)(sm + (byte ^ ((t & 7) << 4))) = o;
    }
  }
  __syncthreads();

  // XT (B-operand) fragment address components; rows >=49 read junk, discarded
  int xbase[4], xsw[4];
#pragma unroll
  for (int mt = 0; mt < 4; ++mt) {
    int row = mt * 16 + l15;
    xbase[mt] = row * 1024;
    xsw[mt]   = (row & 7) << 4;
  }

  // this wave's weight fragment stream (fragment-order layout, 1 KB contiguous each)
  const short* wgb0 = wcvt + wave * 1024 + lane * 8;

#define LDWP(P, OFF) __builtin_bit_cast(bf16x8, *(const short8*)((P) + (OFF)))
#define LDX(MT, C) __builtin_bit_cast(bf16x8, *(const short8*)(sm + xbase[MT] + ((C) ^ xsw[MT])))

  // ---- pass 1: Q and K projections fused over ONE XT read stream ----
  {
    const short* wq = wgb0;
    const short* wk = wgb0 + 262144;
    float4v aq[2][4], ak[2][4];
#pragma unroll
    for (int nt = 0; nt < 2; ++nt)
#pragma unroll
      for (int mt = 0; mt < 4; ++mt) { aq[nt][mt] = (float4v)0.f; ak[nt][mt] = (float4v)0.f; }

    bf16x8 uq0 = LDWP(wq, 0), uq1 = LDWP(wq, 512);
    bf16x8 uk0 = LDWP(wk, 0), uk1 = LDWP(wk, 512);

#pragma unroll 1
    for (int kk = 0; kk < 16; ++kk) {
      const int nko = ((kk + 1) & 15) * 16384;   // wraps; final prefetch discarded
      bf16x8 nq0 = LDWP(wq, nko), nq1 = LDWP(wq, nko + 512);
      bf16x8 nk0 = LDWP(wk, nko), nk1 = LDWP(wk, nko + 512);
      const int c_ = kk * 64 + ckof;
      bf16x8 x0 = LDX(0, c_), x1 = LDX(1, c_), x2 = LDX(2, c_), x3 = LDX(3, c_);
      __builtin_amdgcn_s_setprio(1);
      aq[0][0] = __builtin_amdgcn_mfma_f32_16x16x32_bf16(uq0, x0, aq[0][0], 0, 0, 0);
      aq[1][0] = __builtin_amdgcn_mfma_f32_16x16x32_bf16(uq1, x0, aq[1][0], 0, 0, 0);
      ak[0][0] = __builtin_amdgcn_mfma_f32_16x16x32_bf16(uk0, x0, ak[0][0], 0, 0, 0);
      ak[1][0] = __builtin_amdgcn_mfma_f32_16x16x32_bf16(uk1, x0, ak[1][0], 0, 0, 0);
      aq[0][1] = __builtin_amdgcn_mfma_f32_16x16x32_bf16(uq0, x1, aq[0][1], 0, 0, 0);
      aq[1][1] = __builtin_amdgcn_mfma_f32_16x16x32_bf16(uq1, x1, aq[1][1], 0, 0, 0);
      ak[0][1] = __builtin_amdgcn_mfma_f32_16x16x32_bf16(uk0, x1, ak[0][1], 0, 0, 0);
      ak[1][1] = __builtin_amdgcn_mfma_f32_16x16x32_bf16(uk1, x1, ak[1][1], 0, 0, 0);
      aq[0][2] = __builtin_amdgcn_mfma_f32_16x16x32_bf16(uq0, x2, aq[0][2], 0, 0, 0);
      aq[1][2] = __builtin_amdgcn_mfma_f32_16x16x32_bf16(uq1, x2, aq[1][2], 0, 0, 0);
      ak[0][2] = __builtin_amdgcn_mfma_f32_16x16x32_bf16(uk0, x2, ak[0][2], 0, 0, 0);
      ak[1][2] = __builtin_amdgcn_mfma_f32_16x16x32_bf16(uk1, x2, ak[1][2], 0, 0, 0);
      aq[0][3] = __builtin_amdgcn_mfma_f32_16x16x32_bf16(uq0, x3, aq[0][3], 0, 0, 0);
      aq[1][3] = __builtin_amdgcn_mfma_f32_16x16x32_bf16(uq1, x3, aq[1][3], 0, 0, 0);
      ak[0][3] = __builtin_amdgcn_mfma_f32_16x16x32_bf16(uk0, x3, ak[0][3], 0, 0, 0);
      ak[1][3] = __builtin_amdgcn_mfma_f32_16x16x32_bf16(uk1, x3, ak[1][3], 0, 0, 0);
      __builtin_amdgcn_s_setprio(0);
      uq0 = nq0; uq1 = nq1; uk0 = nk0; uk1 = nk1;
    }

    // paired epilogue: one address computation feeds both P_q and P_k stores
#pragma unroll
    for (int nt = 0; nt < 2; ++nt) {
      int o0 = wcol + nt * 16 + ig;            // o = o0 + r, r=0..3 (same head)
      float4v bq = *(const float4v*)(qb + o0);
      float4v bk = *(const float4v*)(kb + o0);
#pragma unroll
      for (int r = 0; r < 4; ++r) bq[r] *= 0.125f;   // match pre-scaled W_q
      int dd0 = o0 & 63, sg = o0 >> 6;
#pragma unroll
      for (int mt = 0; mt < 4; ++mt) {
        int t = mt * 16 + l15;
        if (t < 49) {
          int s = t * 8 + sg;
          int addr = (s * 128 + dd0 * 2) ^ pswz(s);
          uint2v pq, pk;
          pq.x = cvtpk(aq[nt][mt][0] + bq[0], aq[nt][mt][1] + bq[1]);
          pq.y = cvtpk(aq[nt][mt][2] + bq[2], aq[nt][mt][3] + bq[3]);
          pk.x = cvtpk(ak[nt][mt][0] + bk[0], ak[nt][mt][1] + bk[1]);
          pk.y = cvtpk(ak[nt][mt][2] + bk[2], ak[nt][mt][3] + bk[3]);
          *(uint2v*)(sm + LDS_PQ + addr) = pq;
          *(uint2v*)(sm + LDS_PK + addr) = pk;
        }
      }
    }
  }

  // ---- pass 2: V projection (depth-2 weight pipeline), epilogue scatters VT ----
  {
    const short* wgb = wgb0 + 2 * 262144;
    float4v acc[2][4];
#pragma unroll
    for (int nt = 0; nt < 2; ++nt)
#pragma unroll
      for (int mt = 0; mt < 4; ++mt) acc[nt][mt] = (float4v)0.f;

    bf16x8 wa0 = LDWP(wgb, 0),     wa1 = LDWP(wgb, 512);
    bf16x8 wb0 = LDWP(wgb, 16384), wb1 = LDWP(wgb, 16384 + 512);
    bf16x8 wc0, wc1, wd0, wd1;

#define GEMM_PHASE(KIDX, W0, W1)                                                          \
    do {                                                                                  \
      const int c_ = (KIDX) * 64 + ckof;                                                  \
      bf16x8 x0_ = LDX(0, c_), x1_ = LDX(1, c_), x2_ = LDX(2, c_), x3_ = LDX(3, c_);      \
      __builtin_amdgcn_s_setprio(1);                                                      \
      acc[0][0] = __builtin_amdgcn_mfma_f32_16x16x32_bf16(W0, x0_, acc[0][0], 0, 0, 0);   \
      acc[1][0] = __builtin_amdgcn_mfma_f32_16x16x32_bf16(W1, x0_, acc[1][0], 0, 0, 0);   \
      acc[0][1] = __builtin_amdgcn_mfma_f32_16x16x32_bf16(W0, x1_, acc[0][1], 0, 0, 0);   \
      acc[1][1] = __builtin_amdgcn_mfma_f32_16x16x32_bf16(W1, x1_, acc[1][1], 0, 0, 0);   \
      acc[0][2] = __builtin_amdgcn_mfma_f32_16x16x32_bf16(W0, x2_, acc[0][2], 0, 0, 0);   \
      acc[1][2] = __builtin_amdgcn_mfma_f32_16x16x32_bf16(W1, x2_, acc[1][2], 0, 0, 0);   \
      acc[0][3] = __builtin_amdgcn_mfma_f32_16x16x32_bf16(W0, x3_, acc[0][3], 0, 0, 0);   \
      acc[1][3] = __builtin_amdgcn_mfma_f32_16x16x32_bf16(W1, x3_, acc[1][3], 0, 0, 0);   \
      __builtin_amdgcn_s_setprio(0);                                                      \
    } while (0)

#pragma unroll 1
    for (int kk = 0; kk < 16; kk += 4) {
      wc0 = LDWP(wgb, ((kk + 2) & 15) * 16384); wc1 = LDWP(wgb, ((kk + 2) & 15) * 16384 + 512);
      GEMM_PHASE(kk, wa0, wa1);
      wd0 = LDWP(wgb, ((kk + 3) & 15) * 16384); wd1 = LDWP(wgb, ((kk + 3) & 15) * 16384 + 512);
      GEMM_PHASE(kk + 1, wb0, wb1);
      wa0 = LDWP(wgb, ((kk + 4) & 15) * 16384); wa1 = LDWP(wgb, ((kk + 4) & 15) * 16384 + 512);
      GEMM_PHASE(kk + 2, wc0, wc1);
      wb0 = LDWP(wgb, ((kk + 5) & 15) * 16384); wb1 = LDWP(wgb, ((kk + 5) & 15) * 16384 + 512);
      GEMM_PHASE(kk + 3, wd0, wd1);
    }
#undef GEMM_PHASE

    __syncthreads();  // all waves done reading XT; region A becomes VT [dd][h2*56+tp]
#pragma unroll
    for (int nt = 0; nt < 2; ++nt) {
      int o0 = wcol + nt * 16 + ig;
      float4v bv = *(const float4v*)(vb + o0);
      int dd0 = o0 & 63, sg = o0 >> 6;
#pragma unroll
      for (int mt = 0; mt < 4; ++mt) {
        int t = mt * 16 + l15;
        if (t < 49) {
          int s = t * 8 + sg;
          int h2 = (s * 1339) >> 16;       // s / 49 (destination head stripe)
          int colb = h2 * 112 + (s - h2 * 49) * 2;
#pragma unroll
          for (int r = 0; r < 4; ++r) {
            int dd = dd0 + r;
            *(unsigned short*)(sm + ((dd * 896 + colb) ^ ((dd & 7) << 4))) =
                f2bf(acc[nt][mt][r] + bv[r]);
          }
        }
      }
    }
    // zero VT junk cols tp=49..55 of every head stripe: never written above,
    // read by PV k-slots whose attn-B is exactly 0 -- 0*NaN=NaN (r9 lesson).
    if (tid < 512) {
      int h2 = tid >> 6, dd = tid & 63;
      int rowb = dd * 896 + h2 * 112;
      int swz = (dd & 7) << 4;
#pragma unroll
      for (int q = 49; q < 56; ++q)
        *(unsigned short*)(sm + ((rowb + q * 2) ^ swz)) = 0;
    }
    // VT-ready sync happens after softmax, just before PV
  }

  // ---- attention: wave pair (h, h+8) -> head h; mh owns i-tiles {mh*2, mh*2+1} ----
  // QK^T swapped: D[row=j][col=i]; scr[jt][it], lane: i = (mh*2+it)*16+l15, j = jt*16+ig+r
  float4v scr[4][2];
#pragma unroll
  for (int jt = 0; jt < 4; ++jt)
#pragma unroll
    for (int it = 0; it < 2; ++it) scr[jt][it] = (float4v)0.f;

#pragma unroll
  for (int ks = 0; ks < 2; ++ks) {
    const int dd = ks * 32 + l4 * 8;
    bf16x8 kf[4], qf[2];
#pragma unroll
    for (int jt = 0; jt < 4; ++jt) {
      int s = h * 49 + jt * 16 + l15;            // rows beyond head: junk, masked by index
      int flat = s * 128 + dd * 2;
      kf[jt] = __builtin_bit_cast(bf16x8, *(const short8*)(sm + LDS_PK + (flat ^ pswz(s))));
    }
#pragma unroll
    for (int it = 0; it < 2; ++it) {
      int s = h * 49 + (mh * 2 + it) * 16 + l15;
      int flat = s * 128 + dd * 2;
      qf[it] = __builtin_bit_cast(bf16x8, *(const short8*)(sm + LDS_PQ + (flat ^ pswz(s))));
    }
    __builtin_amdgcn_s_setprio(1);
#pragma unroll
    for (int jt = 0; jt < 4; ++jt)
#pragma unroll
      for (int it = 0; it < 2; ++it)
        scr[jt][it] = __builtin_amdgcn_mfma_f32_16x16x32_bf16(kf[jt], qf[it], scr[jt][it], 0, 0, 0);
    __builtin_amdgcn_s_setprio(0);
  }

  // softmax: lane holds 16 j-values (jt x r) of column i; bias from the L2-resident
  // bexp[h][i][j] table (aligned float4 per jt). Scores pre-scaled via W_q.
  const float* bx = bexp + h * 2744;
#pragma unroll
  for (int it = 0; it < 2; ++it) {
    int i = (mh * 2 + it) * 16 + l15;
    const float* bi = bx + ((i > 48) ? 48 : i) * 56 + ig;
    float mx = -1e30f;
#pragma unroll
    for (int jt = 0; jt < 4; ++jt) {
      float4v b4 = *(const float4v*)(bi + jt * 16);
#pragma unroll
      for (int r = 0; r < 4; ++r) {
        int j = jt * 16 + ig + r;
        float v = (i < 49 && j < 49) ? scr[jt][it][r] + b4[r] : -1e30f;
        scr[jt][it][r] = v;
        mx = fmaxf(mx, v);
      }
    }
    mx = fmaxf(mx, __shfl_xor(mx, 16));
    mx = fmaxf(mx, __shfl_xor(mx, 32));
    float ssum = 0.f;
#pragma unroll
    for (int jt = 0; jt < 4; ++jt)
#pragma unroll
      for (int r = 0; r < 4; ++r) {
        float e = __expf(scr[jt][it][r] - mx);   // -1e30 slots underflow to 0
        scr[jt][it][r] = e;
        ssum += e;
      }
    ssum += __shfl_xor(ssum, 16);
    ssum += __shfl_xor(ssum, 32);
    float inv = 1.f / ssum;
#pragma unroll
    for (int jt = 0; jt < 4; ++jt)
#pragma unroll
      for (int r = 0; r < 4; ++r) scr[jt][it][r] *= inv;
  }

  // overlay attn IN PLACE into head h's own P_q rows (s = h*49+i); rows are
  // mh-disjoint per wave pair, cross-head stragglers read only masked finite junk.
#pragma unroll
  for (int it = 0; it < 2; ++it) {
    int i = (mh * 2 + it) * 16 + l15;
    if (i < 49) {
      int s = h * 49 + i;
      int rowb = s * 128;
      int swz = pswz(s);
#pragma unroll
      for (int jt = 0; jt < 4; ++jt) {
        uint2v pk2;
        pk2.x = cvtpk(scr[jt][it][0], scr[jt][it][1]);
        pk2.y = cvtpk(scr[jt][it][2], scr[jt][it][3]);
        *(uint2v*)(sm + LDS_PQ + ((rowb + jt * 32 + ig * 2) ^ swz)) = pk2;
      }
    }
  }

  __syncthreads();  // VT (incl. pad zeros) + all overlays complete before PV

  // PV swapped: A = VT[dd][h*56+tp] (dt-tiles), B = attn rows (tt-tiles); D = out^T
  float4v oacc[4][2];   // [dt][tt]
#pragma unroll
  for (int dt = 0; dt < 4; ++dt)
#pragma unroll
    for (int tt = 0; tt < 2; ++tt) oacc[dt][tt] = (float4v)0.f;

#pragma unroll
  for (int ks = 0; ks < 2; ++ks) {
    const int tp0 = ks * 32 + l4 * 8;     // tp 56..63 lands in next stripe: finite x zero-B
    bf16x8 vf[4], af[2];
#pragma unroll
    for (int dt = 0; dt < 4; ++dt) {
      int dd = dt * 16 + l15;
      vf[dt] = __builtin_bit_cast(bf16x8,
          *(const short8*)(sm + ((dd * 896 + h * 112 + tp0 * 2) ^ ((dd & 7) << 4))));
    }
#pragma unroll
    for (int tt = 0; tt < 2; ++tt) {
      int t = (mh * 2 + tt) * 16 + l15;
      int tr = (t > 48) ? 48 : t;         // junk cols (t>=49) read row 48; discarded
      int s = h * 49 + tr;
      af[tt] = __builtin_bit_cast(bf16x8,
          *(const short8*)(sm + LDS_PQ + ((s * 128 + tp0 * 2) ^ pswz(s))));
    }
    __builtin_amdgcn_s_setprio(1);
#pragma unroll
    for (int dt = 0; dt < 4; ++dt)
#pragma unroll
      for (int tt = 0; tt < 2; ++tt)
        oacc[dt][tt] = __builtin_amdgcn_mfma_f32_16x16x32_bf16(vf[dt], af[tt], oacc[dt][tt], 0, 0, 0);
    __builtin_amdgcn_s_setprio(0);
  }

  // output: flat [b][wi][h][t'][dd]; float4 stores (r -> 4 consecutive dd)
  float* op = out + (size_t)bwi * 25088 + h * 3136;
#pragma unroll
  for (int tt = 0; tt < 2; ++tt) {
    int t = (mh * 2 + tt) * 16 + l15;
    if (t < 49) {
#pragma unroll
      for (int dt = 0; dt < 4; ++dt)
        *(float4v*)(op + t * 64 + dt * 16 + ig) = oacc[dt][tt];
    }
  }
#undef LDWP
#undef LDX
}

extern "C" void kernel_launch(void* const* d_in, const int* in_sizes, int n_in,
                              void* d_out, int out_size, void* d_ws, size_t ws_size,
                              hipStream_t stream) {
  const float* x    = (const float*)d_in[0];
  const float* q_w  = (const float*)d_in[1];
  const float* q_b  = (const float*)d_in[2];
  const float* k_w  = (const float*)d_in[3];
  const float* k_b  = (const float*)d_in[4];
  const float* v_w  = (const float*)d_in[5];
  const float* v_b  = (const float*)d_in[6];
  const float* btab = (const float*)d_in[7];
  short* wcvt = (short*)d_ws;                              // 1.5 MB fragment-order weights
  float* bexp = (float*)((char*)d_ws + 3 * 262144 * 2);    // 22016 f32 (88 KB) bias table

  hipLaunchKernelGGL(wconv_kernel, dim3(384), dim3(256), 0, stream, q_w, k_w, v_w, wcvt);
  hipLaunchKernelGGL(bexp_kernel, dim3(86), dim3(256), 0, stream, btab, bexp);
  hipLaunchKernelGGL(wattn_kernel, dim3(1024), dim3(1024), 0, stream,
                     x, wcvt, q_b, k_b, v_b, bexp, (float*)d_out);
}